// Round 1
// baseline (383.587 us; speedup 1.0000x reference)
//
#include <hip/hip_runtime.h>

#define NN 2048
#define PP 2048
#define QQ 64

__device__ __forceinline__ float fast_rcp(float x) { return __builtin_amdgcn_rcpf(x); }

// tanh(x) = 1 - 2/(e^{2x}+1); saturates correctly for |x| large (rcp(inf)=0)
__device__ __forceinline__ float fast_tanh(float x) {
    float t = __expf(2.0f * x);
    return 1.0f - 2.0f * __builtin_amdgcn_rcpf(t + 1.0f);
}

// ---------------- Kernel A: attention logits + masked softmax + coeff ----------------
__global__ __launch_bounds__(256) void attn_kernel(
    const float* __restrict__ pc,   // phase_coords (N,4)
    const float* __restrict__ cp,   // coeff_position (P,2)
    const float* __restrict__ cv,   // coeff_values (P,2)
    const float* __restrict__ w1, const float* __restrict__ b1,
    const float* __restrict__ w2, const float* __restrict__ b2,
    const float* __restrict__ w3, const float* __restrict__ b3,
    float* __restrict__ coeff_out)  // (N,2)
{
    __shared__ float slog[PP];
    __shared__ float sred[16];

    const int n = blockIdx.x;
    const int t = threadIdx.x;
    const int wid = t >> 6, lane = t & 63;

    const float x0 = pc[n*4+0], x1 = pc[n*4+1];
    const float v0 = pc[n*4+2], v1 = pc[n*4+3];
    const float rinv = __builtin_amdgcn_rsqf(v0*v0 + v1*v1 + 1e-16f);
    const float a0 = v0 * rinv, a1 = v1 * rinv;
    const float b3v = b3[0];

    #pragma unroll 1
    for (int i = 0; i < PP/256; ++i) {
        const int p = i*256 + t;
        const float2 cpp = ((const float2*)cp)[p];
        const float r0 = x0 - cpp.x;
        const float r1 = x1 - cpp.y;
        const float dist = sqrtf(r0*r0 + r1*r1 + 1e-16f);
        const float pos  = r0*a0 + r1*a1;
        const float angl = pos * fast_rcp(dist + 1e-8f);

        float in[6] = {x0, x1, v0, v1, angl, pos};

        float h1[32];
        #pragma unroll
        for (int k = 0; k < 32; ++k) h1[k] = b1[k];
        #pragma unroll
        for (int j = 0; j < 6; ++j) {
            const float xv = in[j];
            #pragma unroll
            for (int k = 0; k < 32; ++k) h1[k] = fmaf(xv, w1[j*32+k], h1[k]);
        }
        #pragma unroll
        for (int k = 0; k < 32; ++k) h1[k] = fast_tanh(h1[k]);

        float h2[32];
        #pragma unroll
        for (int k = 0; k < 32; ++k) h2[k] = b2[k];
        #pragma unroll
        for (int j = 0; j < 32; ++j) {
            const float xv = h1[j];
            #pragma unroll
            for (int k = 0; k < 32; ++k) h2[k] = fmaf(xv, w2[j*32+k], h2[k]);
        }

        float lg = b3v;
        #pragma unroll
        for (int k = 0; k < 32; ++k) lg = fmaf(fast_tanh(h2[k]), w3[k], lg);

        slog[p] = (pos > 0.0f) ? lg : -1e30f;
    }
    __syncthreads();

    // pass 2: masked softmax + aw @ coeff_values
    float m = -3.4e38f;
    #pragma unroll
    for (int i = 0; i < PP/256; ++i) m = fmaxf(m, slog[i*256 + t]);
    #pragma unroll
    for (int off = 32; off; off >>= 1) m = fmaxf(m, __shfl_xor(m, off));
    if (lane == 0) sred[wid] = m;
    __syncthreads();
    m = fmaxf(fmaxf(sred[0], sred[1]), fmaxf(sred[2], sred[3]));

    float s = 0.0f, q0 = 0.0f, q1 = 0.0f;
    #pragma unroll 1
    for (int i = 0; i < PP/256; ++i) {
        const int p = i*256 + t;
        const float e = __expf(slog[p] - m);
        const float2 cvv = ((const float2*)cv)[p];
        s += e;
        q0 = fmaf(e, cvv.x, q0);
        q1 = fmaf(e, cvv.y, q1);
    }
    #pragma unroll
    for (int off = 32; off; off >>= 1) {
        s  += __shfl_xor(s, off);
        q0 += __shfl_xor(q0, off);
        q1 += __shfl_xor(q1, off);
    }
    __syncthreads();   // sred[0..3] reads done before reuse of sred
    if (lane == 0) {
        sred[4 + wid*3 + 0] = s;
        sred[4 + wid*3 + 1] = q0;
        sred[4 + wid*3 + 2] = q1;
    }
    __syncthreads();
    if (t == 0) {
        float S = 0.0f, Q0 = 0.0f, Q1 = 0.0f;
        #pragma unroll
        for (int w = 0; w < 4; ++w) {
            S  += sred[4 + w*3 + 0];
            Q0 += sred[4 + w*3 + 1];
            Q1 += sred[4 + w*3 + 2];
        }
        const float invS = fast_rcp(S);
        coeff_out[n*2+0] = __expf(-Q0 * invS);
        coeff_out[n*2+1] = __expf(-Q1 * invS);
    }
}

// ------- Kernel C: green MLP (g0 + 64 quad points), quad reduce, res, final -------
__global__ __launch_bounds__(256) void green_kernel(
    const float* __restrict__ pc,   // phase_coords (N,4)
    const float* __restrict__ bc,   // boundary_coords (N,4)
    const float* __restrict__ skc,  // scattering_kernel_coords (Q,2)
    const float* __restrict__ sk,   // scattering_kernel (Q,)
    const float* __restrict__ vw,   // velocity_weights (Q,)
    const float* __restrict__ gw1, const float* __restrict__ gb1,
    const float* __restrict__ gw2, const float* __restrict__ gb2,
    const float* __restrict__ gw3, const float* __restrict__ gb3,
    const float* __restrict__ rw,  const float* __restrict__ rb,
    const float* __restrict__ fw,  const float* __restrict__ fb,
    const float* __restrict__ coeff,  // (N,2) from kernel A
    float* __restrict__ out)          // (N,1)
{
    __shared__ float shA[4][64];
    __shared__ float shB[4][64];
    __shared__ float sg0[64];
    __shared__ float squad[64];

    const int n = blockIdx.x;
    const int t = threadIdx.x;
    const int sub = t >> 6, k = t & 63;

    // per-thread weight columns (loop-invariant across the 17 iterations)
    float w1r[10], w2r[64], w3r[64];
    #pragma unroll
    for (int j = 0; j < 10; ++j) w1r[j] = gw1[j*64 + k];
    #pragma unroll
    for (int j = 0; j < 64; ++j) w2r[j] = gw2[j*64 + k];
    #pragma unroll
    for (int j = 0; j < 64; ++j) w3r[j] = gw3[j*64 + k];
    const float b1r = gb1[k], b2r = gb2[k], b3r = gb3[k];

    const float x0 = pc[n*4+0], x1 = pc[n*4+1], v0 = pc[n*4+2], v1 = pc[n*4+3];
    const float xp0 = bc[n*4+0], xp1 = bc[n*4+1], vp0 = bc[n*4+2], vp1 = bc[n*4+3];
    const float c0 = coeff[n*2+0], c1 = coeff[n*2+1];

    float qacc = 0.0f;

    #pragma unroll 1
    for (int it = 0; it < 17; ++it) {
        float i6, i7, wq;
        if (it == 0) {               // g0 point: input = [x,v,xp,vp,coeff]
            i6 = vp0; i7 = vp1; wq = 0.0f;
        } else {                     // quad point: input = [x,v,xp,skc_q,coeff]
            const int q = (it-1)*4 + sub;
            i6 = skc[q*2+0]; i7 = skc[q*2+1];
            wq = (1.0f - sk[q]) * vw[q];
        }

        // layer 1 (10 -> 64)
        float a = b1r;
        a = fmaf(x0,  w1r[0], a); a = fmaf(x1,  w1r[1], a);
        a = fmaf(v0,  w1r[2], a); a = fmaf(v1,  w1r[3], a);
        a = fmaf(xp0, w1r[4], a); a = fmaf(xp1, w1r[5], a);
        a = fmaf(i6,  w1r[6], a); a = fmaf(i7,  w1r[7], a);
        a = fmaf(c0,  w1r[8], a); a = fmaf(c1,  w1r[9], a);
        a = fast_tanh(a);
        shA[sub][k] = a;            // wave-private LDS: no __syncthreads needed

        // layer 2 (64 -> 64)
        float b = b2r;
        #pragma unroll
        for (int j = 0; j < 64; j += 4) {
            const float4 h = *(const float4*)&shA[sub][j];
            b = fmaf(h.x, w2r[j+0], b); b = fmaf(h.y, w2r[j+1], b);
            b = fmaf(h.z, w2r[j+2], b); b = fmaf(h.w, w2r[j+3], b);
        }
        b = fast_tanh(b);
        shB[sub][k] = b;

        // layer 3 (64 -> 64)
        float c = b3r;
        #pragma unroll
        for (int j = 0; j < 64; j += 4) {
            const float4 h = *(const float4*)&shB[sub][j];
            c = fmaf(h.x, w3r[j+0], c); c = fmaf(h.y, w3r[j+1], c);
            c = fmaf(h.z, w3r[j+2], c); c = fmaf(h.w, w3r[j+3], c);
        }
        c = fast_tanh(c);
        const float g = __expf(c);

        if (it == 0) {
            if (sub == 0) sg0[k] = g;   // wave-private (only wave 0 reads later)
        } else {
            qacc += wq * g;
        }
    }

    // reduce quad over the 4 sub-waves
    shA[sub][k] = qacc;
    __syncthreads();

    if (sub == 0) {
        squad[k] = shA[0][k] + shA[1][k] + shA[2][k] + shA[3][k];
        // res = tanh(quad @ res_w + res_b)   (wave-private squad)
        float racc = rb[k];
        #pragma unroll
        for (int j = 0; j < 64; j += 4) {
            const float4 qd = *(const float4*)&squad[j];
            racc = fmaf(qd.x, rw[(j+0)*64 + k], racc);
            racc = fmaf(qd.y, rw[(j+1)*64 + k], racc);
            racc = fmaf(qd.z, rw[(j+2)*64 + k], racc);
            racc = fmaf(qd.w, rw[(j+3)*64 + k], racc);
        }
        const float resv = fast_tanh(racc);
        const float o = sg0[k] + resv;

        float term = o * fw[k];
        #pragma unroll
        for (int off = 32; off; off >>= 1) term += __shfl_xor(term, off);
        if (k == 0) out[n] = term + fb[0];
    }
}

extern "C" void kernel_launch(void* const* d_in, const int* in_sizes, int n_in,
                              void* d_out, int out_size, void* d_ws, size_t ws_size,
                              hipStream_t stream) {
    const float* pc  = (const float*)d_in[0];
    const float* bc  = (const float*)d_in[1];
    const float* cp  = (const float*)d_in[2];
    const float* cv  = (const float*)d_in[3];
    const float* skc = (const float*)d_in[4];
    const float* sk  = (const float*)d_in[5];
    const float* vw  = (const float*)d_in[6];
    const float* aw1 = (const float*)d_in[7];
    const float* ab1 = (const float*)d_in[8];
    const float* aw2 = (const float*)d_in[9];
    const float* ab2 = (const float*)d_in[10];
    const float* aw3 = (const float*)d_in[11];
    const float* ab3 = (const float*)d_in[12];
    const float* gw1 = (const float*)d_in[13];
    const float* gb1 = (const float*)d_in[14];
    const float* gw2 = (const float*)d_in[15];
    const float* gb2 = (const float*)d_in[16];
    const float* gw3 = (const float*)d_in[17];
    const float* gb3 = (const float*)d_in[18];
    const float* rw  = (const float*)d_in[19];
    const float* rb  = (const float*)d_in[20];
    const float* fw  = (const float*)d_in[21];
    const float* fb  = (const float*)d_in[22];

    float* coeff = (float*)d_ws;          // N*2 floats
    float* outp  = (float*)d_out;

    attn_kernel<<<NN, 256, 0, stream>>>(pc, cp, cv, aw1, ab1, aw2, ab2, aw3, ab3, coeff);
    green_kernel<<<NN, 256, 0, stream>>>(pc, bc, skc, sk, vw,
                                         gw1, gb1, gw2, gb2, gw3, gb3,
                                         rw, rb, fw, fb, coeff, outp);
}

// Round 3
// 179.819 us; speedup vs baseline: 2.1332x; 2.1332x over previous
//
#include <hip/hip_runtime.h>

#define NN 2048
#define PP 2048
#define QQ 64

typedef __attribute__((ext_vector_type(8))) short short8;
typedef __attribute__((ext_vector_type(4))) float f32x4;

__device__ __forceinline__ float fast_rcp(float x) { return __builtin_amdgcn_rcpf(x); }

// tanh(x) = 1 - 2/(e^{2x}+1); saturates correctly for |x| large (rcp(inf)=0)
__device__ __forceinline__ float fast_tanh(float x) {
    float t = __expf(x + x);
    return 1.0f - 2.0f * __builtin_amdgcn_rcpf(t + 1.0f);
}

// round-to-nearest-even bf16 bits of a float
__device__ __forceinline__ unsigned bf16_bits(float f) {
    unsigned u = __builtin_bit_cast(unsigned, f);
    u += 0x7FFFu + ((u >> 16) & 1u);
    return u >> 16;
}
__device__ __forceinline__ unsigned pack_bf16(float lo, float hi) {
    return bf16_bits(lo) | (bf16_bits(hi) << 16);
}

// ---------------- Kernel A: attention logits (MFMA layer2) + masked softmax + coeff ----
__global__ __launch_bounds__(256) void attn_kernel(
    const float* __restrict__ pc,   // phase_coords (N,4)
    const float* __restrict__ cp,   // coeff_position (P,2)
    const float* __restrict__ cv,   // coeff_values (P,2)
    const float* __restrict__ w1, const float* __restrict__ b1,
    const float* __restrict__ w2, const float* __restrict__ b2,
    const float* __restrict__ w3, const float* __restrict__ b3,
    float* __restrict__ coeff_out)  // (N,2)
{
    __shared__ float slog[PP];
    __shared__ float sred[16];

    const int n = blockIdx.x;
    const int t = threadIdx.x;
    const int wid  = t >> 6;
    const int lane = t & 63;
    const int c15  = lane & 15;        // MFMA row (pair-in-tile) / col (neuron)
    const int kg   = lane >> 4;        // k-group 0..3
    const int k0   = kg * 8;

    const float x0 = pc[n*4+0], x1 = pc[n*4+1];
    const float v0 = pc[n*4+2], v1 = pc[n*4+3];
    const float rinv = __builtin_amdgcn_rsqf(v0*v0 + v1*v1 + 1e-16f);
    const float a0 = v0 * rinv, a1 = v1 * rinv;
    const float b3v = b3[0];

    // per-lane layer1 constants: c_n[k] = b1[k] + [x,v] @ w1[0:4,k]; w1 rows 4,5 for angl,pos
    float cfrag[8], w1a[8], w1b[8];
    #pragma unroll
    for (int j = 0; j < 8; ++j) {
        const int k = k0 + j;
        float c = b1[k];
        c = fmaf(x0, w1[0*32+k], c);
        c = fmaf(x1, w1[1*32+k], c);
        c = fmaf(v0, w1[2*32+k], c);
        c = fmaf(v1, w1[3*32+k], c);
        cfrag[j] = c;
        w1a[j] = w1[4*32+k];
        w1b[j] = w1[5*32+k];
    }

    // B-fragments: w2 (32x32) as bf16, cols [c15] and [c15+16], k = k0+j
    union BF { short8 s8; unsigned u[4]; } B0, B1;
    #pragma unroll
    for (int j2 = 0; j2 < 4; ++j2) {
        const int ka = k0 + 2*j2, kb = ka + 1;
        B0.u[j2] = pack_bf16(w2[ka*32 + c15],      w2[kb*32 + c15]);
        B1.u[j2] = pack_bf16(w2[ka*32 + c15 + 16], w2[kb*32 + c15 + 16]);
    }
    const float w3c0 = w3[c15], w3c1 = w3[c15 + 16];
    const float b2c0 = b2[c15], b2c1 = b2[c15 + 16];

    // ---- pass 1: logits, 16 pairs per wave-tile ----
    #pragma unroll 1
    for (int tile = wid; tile < PP/16; tile += 4) {
        const int p = tile*16 + c15;
        const float2 cpp = ((const float2*)cp)[p];
        const float r0 = x0 - cpp.x;
        const float r1 = x1 - cpp.y;
        const float dist = sqrtf(r0*r0 + r1*r1 + 1e-16f);
        const float pos  = fmaf(r0, a0, r1*a1);
        const float angl = pos * fast_rcp(dist + 1e-8f);

        // h1 (8 values for this lane's k-slice), tanh, pack to bf16 A-frag
        union AF { short8 s8; unsigned u[4]; } A;
        #pragma unroll
        for (int j2 = 0; j2 < 4; ++j2) {
            const float ha = fast_tanh(fmaf(angl, w1a[2*j2+0], fmaf(pos, w1b[2*j2+0], cfrag[2*j2+0])));
            const float hb = fast_tanh(fmaf(angl, w1a[2*j2+1], fmaf(pos, w1b[2*j2+1], cfrag[2*j2+1])));
            A.u[j2] = pack_bf16(ha, hb);
        }

        f32x4 acc0 = {b2c0, b2c0, b2c0, b2c0};
        f32x4 acc1 = {b2c1, b2c1, b2c1, b2c1};
        acc0 = __builtin_amdgcn_mfma_f32_16x16x32_bf16(A.s8, B0.s8, acc0, 0, 0, 0);
        acc1 = __builtin_amdgcn_mfma_f32_16x16x32_bf16(A.s8, B1.s8, acc1, 0, 0, 0);

        // logits: lg[r] = sum over 32 neurons of tanh(h2)*w3  (partial: 2 cols per lane)
        float lg[4];
        #pragma unroll
        for (int r = 0; r < 4; ++r)
            lg[r] = fmaf(fast_tanh(acc0[r]), w3c0, fast_tanh(acc1[r]) * w3c1);

        #pragma unroll
        for (int off = 1; off < 16; off <<= 1) {
            #pragma unroll
            for (int r = 0; r < 4; ++r) lg[r] += __shfl_xor(lg[r], off);
        }

        // mask: row pair (kg*4+r)'s pos lives in lane (kg*4+r)
        float lgm[4];
        #pragma unroll
        for (int r = 0; r < 4; ++r) {
            const float posr = __shfl(pos, kg*4 + r);
            lgm[r] = (posr > 0.0f) ? (lg[r] + b3v) : -1e30f;
        }
        if (c15 == 0) {
            float4 o = make_float4(lgm[0], lgm[1], lgm[2], lgm[3]);
            *(float4*)&slog[tile*16 + kg*4] = o;
        }
    }
    __syncthreads();

    // ---- pass 2: masked softmax + aw @ coeff_values ----
    float m = -3.4e38f;
    #pragma unroll
    for (int i = 0; i < PP/256; ++i) m = fmaxf(m, slog[i*256 + t]);
    #pragma unroll
    for (int off = 32; off; off >>= 1) m = fmaxf(m, __shfl_xor(m, off));
    if (lane == 0) sred[wid] = m;
    __syncthreads();
    m = fmaxf(fmaxf(sred[0], sred[1]), fmaxf(sred[2], sred[3]));

    float s = 0.0f, q0 = 0.0f, q1 = 0.0f;
    #pragma unroll 1
    for (int i = 0; i < PP/256; ++i) {
        const int p = i*256 + t;
        const float e = __expf(slog[p] - m);
        const float2 cvv = ((const float2*)cv)[p];
        s += e;
        q0 = fmaf(e, cvv.x, q0);
        q1 = fmaf(e, cvv.y, q1);
    }
    #pragma unroll
    for (int off = 32; off; off >>= 1) {
        s  += __shfl_xor(s, off);
        q0 += __shfl_xor(q0, off);
        q1 += __shfl_xor(q1, off);
    }
    __syncthreads();
    if (lane == 0) {
        sred[4 + wid*3 + 0] = s;
        sred[4 + wid*3 + 1] = q0;
        sred[4 + wid*3 + 2] = q1;
    }
    __syncthreads();
    if (t == 0) {
        float S = 0.0f, Q0 = 0.0f, Q1 = 0.0f;
        #pragma unroll
        for (int w = 0; w < 4; ++w) {
            S  += sred[4 + w*3 + 0];
            Q0 += sred[4 + w*3 + 1];
            Q1 += sred[4 + w*3 + 2];
        }
        const float invS = fast_rcp(S);
        coeff_out[n*2+0] = __expf(-Q0 * invS);
        coeff_out[n*2+1] = __expf(-Q1 * invS);
    }
}

// ------- Kernel C: green MLP (g0 + 64 quad points), quad reduce, res, final -------
__global__ __launch_bounds__(256) void green_kernel(
    const float* __restrict__ pc,   // phase_coords (N,4)
    const float* __restrict__ bc,   // boundary_coords (N,4)
    const float* __restrict__ skc,  // scattering_kernel_coords (Q,2)
    const float* __restrict__ sk,   // scattering_kernel (Q,)
    const float* __restrict__ vw,   // velocity_weights (Q,)
    const float* __restrict__ gw1, const float* __restrict__ gb1,
    const float* __restrict__ gw2, const float* __restrict__ gb2,
    const float* __restrict__ gw3, const float* __restrict__ gb3,
    const float* __restrict__ rw,  const float* __restrict__ rb,
    const float* __restrict__ fw,  const float* __restrict__ fb,
    const float* __restrict__ coeff,  // (N,2) from kernel A
    float* __restrict__ out)          // (N,1)
{
    __shared__ float shA[4][64];
    __shared__ float shB[4][64];
    __shared__ float sg0[64];
    __shared__ float squad[64];

    const int n = blockIdx.x;
    const int t = threadIdx.x;
    const int sub = t >> 6, k = t & 63;

    float w1r[10], w2r[64], w3r[64];
    #pragma unroll
    for (int j = 0; j < 10; ++j) w1r[j] = gw1[j*64 + k];
    #pragma unroll
    for (int j = 0; j < 64; ++j) w2r[j] = gw2[j*64 + k];
    #pragma unroll
    for (int j = 0; j < 64; ++j) w3r[j] = gw3[j*64 + k];
    const float b1r = gb1[k], b2r = gb2[k], b3r = gb3[k];

    const float x0 = pc[n*4+0], x1 = pc[n*4+1], v0 = pc[n*4+2], v1 = pc[n*4+3];
    const float xp0 = bc[n*4+0], xp1 = bc[n*4+1], vp0 = bc[n*4+2], vp1 = bc[n*4+3];
    const float c0 = coeff[n*2+0], c1 = coeff[n*2+1];

    float qacc = 0.0f;

    #pragma unroll 1
    for (int it = 0; it < 17; ++it) {
        float i6, i7, wq;
        if (it == 0) {               // g0 point: input = [x,v,xp,vp,coeff]
            i6 = vp0; i7 = vp1; wq = 0.0f;
        } else {                     // quad point: input = [x,v,xp,skc_q,coeff]
            const int q = (it-1)*4 + sub;
            i6 = skc[q*2+0]; i7 = skc[q*2+1];
            wq = (1.0f - sk[q]) * vw[q];
        }

        float a = b1r;
        a = fmaf(x0,  w1r[0], a); a = fmaf(x1,  w1r[1], a);
        a = fmaf(v0,  w1r[2], a); a = fmaf(v1,  w1r[3], a);
        a = fmaf(xp0, w1r[4], a); a = fmaf(xp1, w1r[5], a);
        a = fmaf(i6,  w1r[6], a); a = fmaf(i7,  w1r[7], a);
        a = fmaf(c0,  w1r[8], a); a = fmaf(c1,  w1r[9], a);
        a = fast_tanh(a);
        shA[sub][k] = a;            // wave-private LDS

        float b = b2r;
        #pragma unroll
        for (int j = 0; j < 64; j += 4) {
            const float4 h = *(const float4*)&shA[sub][j];
            b = fmaf(h.x, w2r[j+0], b); b = fmaf(h.y, w2r[j+1], b);
            b = fmaf(h.z, w2r[j+2], b); b = fmaf(h.w, w2r[j+3], b);
        }
        b = fast_tanh(b);
        shB[sub][k] = b;

        float c = b3r;
        #pragma unroll
        for (int j = 0; j < 64; j += 4) {
            const float4 h = *(const float4*)&shB[sub][j];
            c = fmaf(h.x, w3r[j+0], c); c = fmaf(h.y, w3r[j+1], c);
            c = fmaf(h.z, w3r[j+2], c); c = fmaf(h.w, w3r[j+3], c);
        }
        c = fast_tanh(c);
        const float g = __expf(c);

        if (it == 0) {
            if (sub == 0) sg0[k] = g;
        } else {
            qacc += wq * g;
        }
    }

    shA[sub][k] = qacc;
    __syncthreads();

    if (sub == 0) {
        squad[k] = shA[0][k] + shA[1][k] + shA[2][k] + shA[3][k];
        float racc = rb[k];
        #pragma unroll
        for (int j = 0; j < 64; j += 4) {
            const float4 qd = *(const float4*)&squad[j];
            racc = fmaf(qd.x, rw[(j+0)*64 + k], racc);
            racc = fmaf(qd.y, rw[(j+1)*64 + k], racc);
            racc = fmaf(qd.z, rw[(j+2)*64 + k], racc);
            racc = fmaf(qd.w, rw[(j+3)*64 + k], racc);
        }
        const float resv = fast_tanh(racc);
        const float o = sg0[k] + resv;

        float term = o * fw[k];
        #pragma unroll
        for (int off = 32; off; off >>= 1) term += __shfl_xor(term, off);
        if (k == 0) out[n] = term + fb[0];
    }
}

extern "C" void kernel_launch(void* const* d_in, const int* in_sizes, int n_in,
                              void* d_out, int out_size, void* d_ws, size_t ws_size,
                              hipStream_t stream) {
    const float* pc  = (const float*)d_in[0];
    const float* bc  = (const float*)d_in[1];
    const float* cp  = (const float*)d_in[2];
    const float* cv  = (const float*)d_in[3];
    const float* skc = (const float*)d_in[4];
    const float* sk  = (const float*)d_in[5];
    const float* vw  = (const float*)d_in[6];
    const float* aw1 = (const float*)d_in[7];
    const float* ab1 = (const float*)d_in[8];
    const float* aw2 = (const float*)d_in[9];
    const float* ab2 = (const float*)d_in[10];
    const float* aw3 = (const float*)d_in[11];
    const float* ab3 = (const float*)d_in[12];
    const float* gw1 = (const float*)d_in[13];
    const float* gb1 = (const float*)d_in[14];
    const float* gw2 = (const float*)d_in[15];
    const float* gb2 = (const float*)d_in[16];
    const float* gw3 = (const float*)d_in[17];
    const float* gb3 = (const float*)d_in[18];
    const float* rw  = (const float*)d_in[19];
    const float* rb  = (const float*)d_in[20];
    const float* fw  = (const float*)d_in[21];
    const float* fb  = (const float*)d_in[22];

    float* coeff = (float*)d_ws;          // N*2 floats
    float* outp  = (float*)d_out;

    attn_kernel<<<NN, 256, 0, stream>>>(pc, cp, cv, aw1, ab1, aw2, ab2, aw3, ab3, coeff);
    green_kernel<<<NN, 256, 0, stream>>>(pc, bc, skc, sk, vw,
                                         gw1, gb1, gw2, gb2, gw3, gb3,
                                         rw, rb, fw, fb, coeff, outp);
}

// Round 4
// 155.113 us; speedup vs baseline: 2.4730x; 1.1593x over previous
//
#include <hip/hip_runtime.h>

#define NN 2048
#define PP 2048
#define QQ 64

typedef __attribute__((ext_vector_type(8))) short short8;
typedef __attribute__((ext_vector_type(4))) float f32x4;

#if __has_builtin(__builtin_amdgcn_exp2f)
#define EXP2(x) __builtin_amdgcn_exp2f(x)
#else
#define EXP2(x) exp2f(x)
#endif

__device__ __forceinline__ float fast_rcp(float x) { return __builtin_amdgcn_rcpf(x); }

// tanh(x) = 1 - 2/(2^(x*2*log2e)+1); saturates correctly for |x| large (rcp(inf)=0)
__device__ __forceinline__ float fast_tanh(float x) {
    float t = EXP2(x * 2.885390082f);
    return 1.0f - 2.0f * __builtin_amdgcn_rcpf(t + 1.0f);
}

// packed f32x2 -> bf16x2 (RNE), single instruction
__device__ __forceinline__ unsigned cvt_pk_bf16(float lo, float hi) {
    unsigned r;
    asm("v_cvt_pk_bf16_f32 %0, %1, %2" : "=v"(r) : "v"(lo), "v"(hi));
    return r;
}

// ---------------- Kernel A: compaction + MFMA layer2 + masked softmax + coeff ----------
__global__ __launch_bounds__(256) void attn_kernel(
    const float* __restrict__ pc,   // phase_coords (N,4)
    const float* __restrict__ cp,   // coeff_position (P,2)
    const float* __restrict__ cv,   // coeff_values (P,2)
    const float* __restrict__ w1, const float* __restrict__ b1,
    const float* __restrict__ w2, const float* __restrict__ b2,
    const float* __restrict__ w3, const float* __restrict__ b3,
    float* __restrict__ coeff_out)  // (N,2)
{
    __shared__ float slog[PP];
    __shared__ unsigned short slist[PP];
    __shared__ float sred[16];
    __shared__ int scount;

    const int n = blockIdx.x;
    const int t = threadIdx.x;
    const int wid  = t >> 6;
    const int lane = t & 63;
    const int c15  = lane & 15;        // MFMA row (pair-in-tile) / col (neuron)
    const int kg   = lane >> 4;        // k-group 0..3
    const int k0   = kg * 8;

    const float x0 = pc[n*4+0], x1 = pc[n*4+1];
    const float v0 = pc[n*4+2], v1 = pc[n*4+3];
    const float rinv = __builtin_amdgcn_rsqf(v0*v0 + v1*v1 + 1e-16f);
    const float a0 = v0 * rinv, a1 = v1 * rinv;
    const float b3v = b3[0];

    // per-lane layer1 constants: c_n[k] = b1[k] + [x,v] @ w1[0:4,k]; rows 4,5 for angl,pos
    float cfrag[8], w1a[8], w1b[8];
    #pragma unroll
    for (int j = 0; j < 8; ++j) {
        const int k = k0 + j;
        float c = b1[k];
        c = fmaf(x0, w1[0*32+k], c);
        c = fmaf(x1, w1[1*32+k], c);
        c = fmaf(v0, w1[2*32+k], c);
        c = fmaf(v1, w1[3*32+k], c);
        cfrag[j] = c;
        w1a[j] = w1[4*32+k];
        w1b[j] = w1[5*32+k];
    }

    // B-fragments: w2 (32x32) as bf16, cols [c15] and [c15+16], k = k0+j
    union BF { short8 s8; unsigned u[4]; } B0, B1;
    #pragma unroll
    for (int j2 = 0; j2 < 4; ++j2) {
        const int ka = k0 + 2*j2, kb = ka + 1;
        B0.u[j2] = cvt_pk_bf16(w2[ka*32 + c15],      w2[kb*32 + c15]);
        B1.u[j2] = cvt_pk_bf16(w2[ka*32 + c15 + 16], w2[kb*32 + c15 + 16]);
    }
    const float w3c0 = w3[c15], w3c1 = w3[c15 + 16];
    const float b2c0 = b2[c15], b2c1 = b2[c15 + 16];

    if (t == 0) scount = 0;
    __syncthreads();

    // ---- pass 0: pos for all p, init slog, compact unmasked indices ----
    #pragma unroll 1
    for (int i = 0; i < PP/256; ++i) {
        const int p = i*256 + t;
        const float2 cpp = ((const float2*)cp)[p];
        const float pos = fmaf(x0 - cpp.x, a0, (x1 - cpp.y) * a1);
        slog[p] = -1e30f;
        const bool f = pos > 0.0f;
        const unsigned long long mask = __ballot(f);
        int base = 0;
        if (lane == 0 && mask) base = atomicAdd(&scount, __popcll(mask));
        base = __shfl(base, 0);
        if (f) {
            const int idx = base + __popcll(mask & ((1ull << lane) - 1ull));
            slist[idx] = (unsigned short)p;
        }
    }
    __syncthreads();
    const int M  = scount;
    const int Mt = (M + 15) >> 4;   // 16-pair tiles

    // ---- pass 1: logits for compacted pairs only (all unmasked) ----
    #pragma unroll 1
    for (int tile = wid; tile < Mt; tile += 4) {
        const int li = tile*16 + c15;
        const int p  = slist[li < M ? li : 0];
        const float2 cpp = ((const float2*)cp)[p];
        const float r0 = x0 - cpp.x;
        const float r1 = x1 - cpp.y;
        const float dist = sqrtf(r0*r0 + r1*r1 + 1e-16f);
        const float pos  = fmaf(r0, a0, r1*a1);
        const float angl = pos * fast_rcp(dist + 1e-8f);

        union AF { short8 s8; unsigned u[4]; } A;
        #pragma unroll
        for (int j2 = 0; j2 < 4; ++j2) {
            const float ha = fast_tanh(fmaf(angl, w1a[2*j2+0], fmaf(pos, w1b[2*j2+0], cfrag[2*j2+0])));
            const float hb = fast_tanh(fmaf(angl, w1a[2*j2+1], fmaf(pos, w1b[2*j2+1], cfrag[2*j2+1])));
            A.u[j2] = cvt_pk_bf16(ha, hb);
        }

        f32x4 acc0 = {b2c0, b2c0, b2c0, b2c0};
        f32x4 acc1 = {b2c1, b2c1, b2c1, b2c1};
        acc0 = __builtin_amdgcn_mfma_f32_16x16x32_bf16(A.s8, B0.s8, acc0, 0, 0, 0);
        acc1 = __builtin_amdgcn_mfma_f32_16x16x32_bf16(A.s8, B1.s8, acc1, 0, 0, 0);

        float lg[4];
        #pragma unroll
        for (int r = 0; r < 4; ++r)
            lg[r] = fmaf(fast_tanh(acc0[r]), w3c0, fast_tanh(acc1[r]) * w3c1);

        #pragma unroll
        for (int off = 1; off < 16; off <<= 1) {
            #pragma unroll
            for (int r = 0; r < 4; ++r) lg[r] += __shfl_xor(lg[r], off);
        }

        if (c15 == 0) {
            #pragma unroll
            for (int r = 0; r < 4; ++r) {
                const int idx = tile*16 + kg*4 + r;   // row kg*4+r of this tile
                if (idx < M) slog[slist[idx]] = lg[r] + b3v;
            }
        }
    }
    __syncthreads();

    // ---- pass 2: masked softmax + aw @ coeff_values ----
    float m = -3.4e38f;
    #pragma unroll
    for (int i = 0; i < PP/256; ++i) m = fmaxf(m, slog[i*256 + t]);
    #pragma unroll
    for (int off = 32; off; off >>= 1) m = fmaxf(m, __shfl_xor(m, off));
    if (lane == 0) sred[wid] = m;
    __syncthreads();
    m = fmaxf(fmaxf(sred[0], sred[1]), fmaxf(sred[2], sred[3]));

    float s = 0.0f, q0 = 0.0f, q1 = 0.0f;
    #pragma unroll 1
    for (int i = 0; i < PP/256; ++i) {
        const int p = i*256 + t;
        const float e = __expf(slog[p] - m);
        const float2 cvv = ((const float2*)cv)[p];
        s += e;
        q0 = fmaf(e, cvv.x, q0);
        q1 = fmaf(e, cvv.y, q1);
    }
    #pragma unroll
    for (int off = 32; off; off >>= 1) {
        s  += __shfl_xor(s, off);
        q0 += __shfl_xor(q0, off);
        q1 += __shfl_xor(q1, off);
    }
    __syncthreads();
    if (lane == 0) {
        sred[4 + wid*3 + 0] = s;
        sred[4 + wid*3 + 1] = q0;
        sred[4 + wid*3 + 2] = q1;
    }
    __syncthreads();
    if (t == 0) {
        float S = 0.0f, Q0 = 0.0f, Q1 = 0.0f;
        #pragma unroll
        for (int w = 0; w < 4; ++w) {
            S  += sred[4 + w*3 + 0];
            Q0 += sred[4 + w*3 + 1];
            Q1 += sred[4 + w*3 + 2];
        }
        const float invS = fast_rcp(S);
        coeff_out[n*2+0] = __expf(-Q0 * invS);
        coeff_out[n*2+1] = __expf(-Q1 * invS);
    }
}

// 64-dot from wave-private LDS with 4 independent accumulator chains
__device__ __forceinline__ float dot64(const float* __restrict__ sh,
                                       const float* __restrict__ w, float bias) {
    float a0 = bias, a1 = 0.0f, a2 = 0.0f, a3 = 0.0f;
    #pragma unroll
    for (int j = 0; j < 64; j += 4) {
        const float4 h = *(const float4*)&sh[j];
        a0 = fmaf(h.x, w[j+0], a0);
        a1 = fmaf(h.y, w[j+1], a1);
        a2 = fmaf(h.z, w[j+2], a2);
        a3 = fmaf(h.w, w[j+3], a3);
    }
    return (a0 + a1) + (a2 + a3);
}

// ------- Kernel C: green MLP (g0 + 64 quad points), quad reduce, res, final -------
__global__ __launch_bounds__(256) void green_kernel(
    const float* __restrict__ pc,   // phase_coords (N,4)
    const float* __restrict__ bc,   // boundary_coords (N,4)
    const float* __restrict__ skc,  // scattering_kernel_coords (Q,2)
    const float* __restrict__ sk,   // scattering_kernel (Q,)
    const float* __restrict__ vw,   // velocity_weights (Q,)
    const float* __restrict__ gw1, const float* __restrict__ gb1,
    const float* __restrict__ gw2, const float* __restrict__ gb2,
    const float* __restrict__ gw3, const float* __restrict__ gb3,
    const float* __restrict__ rw,  const float* __restrict__ rb,
    const float* __restrict__ fw,  const float* __restrict__ fb,
    const float* __restrict__ coeff,  // (N,2) from kernel A
    float* __restrict__ out)          // (N,1)
{
    __shared__ float shA[4][64];
    __shared__ float shB[4][64];
    __shared__ float sg0[64];
    __shared__ float squad[64];

    const int n = blockIdx.x;
    const int t = threadIdx.x;
    const int sub = t >> 6, k = t & 63;

    float w1r[10], w2r[64], w3r[64];
    #pragma unroll
    for (int j = 0; j < 10; ++j) w1r[j] = gw1[j*64 + k];
    #pragma unroll
    for (int j = 0; j < 64; ++j) w2r[j] = gw2[j*64 + k];
    #pragma unroll
    for (int j = 0; j < 64; ++j) w3r[j] = gw3[j*64 + k];
    const float b1r = gb1[k], b2r = gb2[k], b3r = gb3[k];

    const float x0 = pc[n*4+0], x1 = pc[n*4+1], v0 = pc[n*4+2], v1 = pc[n*4+3];
    const float xp0 = bc[n*4+0], xp1 = bc[n*4+1], vp0 = bc[n*4+2], vp1 = bc[n*4+3];
    const float c0 = coeff[n*2+0], c1 = coeff[n*2+1];

    float qacc = 0.0f;

    // waves 1..3 skip the g0 iteration (wave-private LDS, no barrier in loop)
    #pragma unroll 1
    for (int it = (sub == 0) ? 0 : 1; it < 17; ++it) {
        float i6, i7, wq;
        if (it == 0) {               // g0 point: input = [x,v,xp,vp,coeff]
            i6 = vp0; i7 = vp1; wq = 0.0f;
        } else {                     // quad point: input = [x,v,xp,skc_q,coeff]
            const int q = (it-1)*4 + sub;
            i6 = skc[q*2+0]; i7 = skc[q*2+1];
            wq = (1.0f - sk[q]) * vw[q];
        }

        float a = b1r;
        a = fmaf(x0,  w1r[0], a); a = fmaf(x1,  w1r[1], a);
        a = fmaf(v0,  w1r[2], a); a = fmaf(v1,  w1r[3], a);
        a = fmaf(xp0, w1r[4], a); a = fmaf(xp1, w1r[5], a);
        a = fmaf(i6,  w1r[6], a); a = fmaf(i7,  w1r[7], a);
        a = fmaf(c0,  w1r[8], a); a = fmaf(c1,  w1r[9], a);
        shA[sub][k] = fast_tanh(a);

        const float b = fast_tanh(dot64(shA[sub], w2r, b2r));
        shB[sub][k] = b;

        const float c = fast_tanh(dot64(shB[sub], w3r, b3r));
        const float g = __expf(c);

        if (it == 0) {
            if (sub == 0) sg0[k] = g;
        } else {
            qacc += wq * g;
        }
    }

    shA[sub][k] = qacc;
    __syncthreads();

    if (sub == 0) {
        squad[k] = shA[0][k] + shA[1][k] + shA[2][k] + shA[3][k];
        float r0a = rb[k], r1a = 0.0f, r2a = 0.0f, r3a = 0.0f;
        #pragma unroll
        for (int j = 0; j < 64; j += 4) {
            const float4 qd = *(const float4*)&squad[j];
            r0a = fmaf(qd.x, rw[(j+0)*64 + k], r0a);
            r1a = fmaf(qd.y, rw[(j+1)*64 + k], r1a);
            r2a = fmaf(qd.z, rw[(j+2)*64 + k], r2a);
            r3a = fmaf(qd.w, rw[(j+3)*64 + k], r3a);
        }
        const float resv = fast_tanh((r0a + r1a) + (r2a + r3a));
        const float o = sg0[k] + resv;

        float term = o * fw[k];
        #pragma unroll
        for (int off = 32; off; off >>= 1) term += __shfl_xor(term, off);
        if (k == 0) out[n] = term + fb[0];
    }
}

extern "C" void kernel_launch(void* const* d_in, const int* in_sizes, int n_in,
                              void* d_out, int out_size, void* d_ws, size_t ws_size,
                              hipStream_t stream) {
    const float* pc  = (const float*)d_in[0];
    const float* bc  = (const float*)d_in[1];
    const float* cp  = (const float*)d_in[2];
    const float* cv  = (const float*)d_in[3];
    const float* skc = (const float*)d_in[4];
    const float* sk  = (const float*)d_in[5];
    const float* vw  = (const float*)d_in[6];
    const float* aw1 = (const float*)d_in[7];
    const float* ab1 = (const float*)d_in[8];
    const float* aw2 = (const float*)d_in[9];
    const float* ab2 = (const float*)d_in[10];
    const float* aw3 = (const float*)d_in[11];
    const float* ab3 = (const float*)d_in[12];
    const float* gw1 = (const float*)d_in[13];
    const float* gb1 = (const float*)d_in[14];
    const float* gw2 = (const float*)d_in[15];
    const float* gb2 = (const float*)d_in[16];
    const float* gw3 = (const float*)d_in[17];
    const float* gb3 = (const float*)d_in[18];
    const float* rw  = (const float*)d_in[19];
    const float* rb  = (const float*)d_in[20];
    const float* fw  = (const float*)d_in[21];
    const float* fb  = (const float*)d_in[22];

    float* coeff = (float*)d_ws;          // N*2 floats
    float* outp  = (float*)d_out;

    attn_kernel<<<NN, 256, 0, stream>>>(pc, cp, cv, aw1, ab1, aw2, ab2, aw3, ab3, coeff);
    green_kernel<<<NN, 256, 0, stream>>>(pc, bc, skc, sk, vw,
                                         gw1, gb1, gw2, gb2, gw3, gb3,
                                         rw, rb, fw, fb, coeff, outp);
}

// Round 5
// 101.087 us; speedup vs baseline: 3.7946x; 1.5344x over previous
//
#include <hip/hip_runtime.h>

#define NN 2048
#define PP 2048
#define QQ 64
#define GR_ROWS 4
#define GR_SLOTS 80   // 64 quad + g0(slot 64) + 15 pad
#define GR_MT 5       // 16-row M-tiles per row

typedef __attribute__((ext_vector_type(8))) short short8;
typedef __attribute__((ext_vector_type(4))) float f32x4;
typedef __attribute__((ext_vector_type(4))) unsigned u32x4;

union V4 { u32x4 u; short8 s; };

#if __has_builtin(__builtin_amdgcn_exp2f)
#define EXP2(x) __builtin_amdgcn_exp2f(x)
#else
#define EXP2(x) exp2f(x)
#endif

__device__ __forceinline__ float fast_rcp(float x) { return __builtin_amdgcn_rcpf(x); }

// tanh(x) = 1 - 2/(2^(2x*log2e)+1); saturates for |x| large (rcp(inf)=0)
__device__ __forceinline__ float fast_tanh(float x) {
    float t = EXP2(x * 2.885390082f);
    return 1.0f - 2.0f * __builtin_amdgcn_rcpf(t + 1.0f);
}

// packed f32x2 -> bf16x2 (RNE), single instruction
__device__ __forceinline__ unsigned cvt_pk_bf16(float lo, float hi) {
    unsigned r;
    asm("v_cvt_pk_bf16_f32 %0, %1, %2" : "=v"(r) : "v"(lo), "v"(hi));
    return r;
}
// scalar RNE bf16 bits (for single stores)
__device__ __forceinline__ unsigned short bf16_bits(float f) {
    unsigned u = __builtin_bit_cast(unsigned, f);
    u += 0x7FFFu + ((u >> 16) & 1u);
    return (unsigned short)(u >> 16);
}

// ---------------- Kernel A: compaction + MFMA layer2 + compacted softmax ----------
__global__ __launch_bounds__(256) void attn_kernel(
    const float* __restrict__ pc, const float* __restrict__ cp,
    const float* __restrict__ cv,
    const float* __restrict__ w1, const float* __restrict__ b1,
    const float* __restrict__ w2, const float* __restrict__ b2,
    const float* __restrict__ w3, const float* __restrict__ b3,
    float* __restrict__ coeff_out)
{
    __shared__ float slogc[PP];          // compacted logits
    __shared__ unsigned short slist[PP]; // compacted p-indices
    __shared__ float sred[16];
    __shared__ int scount;

    const int n = blockIdx.x;
    const int t = threadIdx.x;
    const int wid  = t >> 6;
    const int lane = t & 63;
    const int c15  = lane & 15;
    const int kg   = lane >> 4;
    const int k0   = kg * 8;

    const float x0 = pc[n*4+0], x1 = pc[n*4+1];
    const float v0 = pc[n*4+2], v1 = pc[n*4+3];
    const float rinv = __builtin_amdgcn_rsqf(v0*v0 + v1*v1 + 1e-16f);
    const float a0 = v0 * rinv, a1 = v1 * rinv;
    const float b3v = b3[0];

    float cfrag[8], w1a[8], w1b[8];
    #pragma unroll
    for (int j = 0; j < 8; ++j) {
        const int k = k0 + j;
        float c = b1[k];
        c = fmaf(x0, w1[0*32+k], c);
        c = fmaf(x1, w1[1*32+k], c);
        c = fmaf(v0, w1[2*32+k], c);
        c = fmaf(v1, w1[3*32+k], c);
        cfrag[j] = c;
        w1a[j] = w1[4*32+k];
        w1b[j] = w1[5*32+k];
    }

    union BF { short8 s8; unsigned u[4]; } B0, B1;
    #pragma unroll
    for (int j2 = 0; j2 < 4; ++j2) {
        const int ka = k0 + 2*j2, kb = ka + 1;
        B0.u[j2] = cvt_pk_bf16(w2[ka*32 + c15],      w2[kb*32 + c15]);
        B1.u[j2] = cvt_pk_bf16(w2[ka*32 + c15 + 16], w2[kb*32 + c15 + 16]);
    }
    const float w3c0 = w3[c15], w3c1 = w3[c15 + 16];
    const float b2c0 = b2[c15], b2c1 = b2[c15 + 16];

    if (t == 0) scount = 0;
    __syncthreads();

    // ---- pass 0: compact unmasked p ----
    #pragma unroll 1
    for (int i = 0; i < PP/256; ++i) {
        const int p = i*256 + t;
        const float2 cpp = ((const float2*)cp)[p];
        const float pos = fmaf(x0 - cpp.x, a0, (x1 - cpp.y) * a1);
        const bool f = pos > 0.0f;
        const unsigned long long mask = __ballot(f);
        int base = 0;
        if (lane == 0 && mask) base = atomicAdd(&scount, __popcll(mask));
        base = __shfl(base, 0);
        if (f) {
            const int idx = base + __popcll(mask & ((1ull << lane) - 1ull));
            slist[idx] = (unsigned short)p;
        }
    }
    __syncthreads();
    const int M  = scount;
    const int Mt = (M + 15) >> 4;

    // ---- pass 1: logits for survivors ----
    #pragma unroll 1
    for (int tile = wid; tile < Mt; tile += 4) {
        const int li = tile*16 + c15;
        const int p  = slist[li < M ? li : 0];
        const float2 cpp = ((const float2*)cp)[p];
        const float r0 = x0 - cpp.x;
        const float r1 = x1 - cpp.y;
        const float dist = sqrtf(r0*r0 + r1*r1 + 1e-16f);
        const float pos  = fmaf(r0, a0, r1*a1);
        const float angl = pos * fast_rcp(dist + 1e-8f);

        union AF { short8 s8; unsigned u[4]; } A;
        #pragma unroll
        for (int j2 = 0; j2 < 4; ++j2) {
            const float ha = fast_tanh(fmaf(angl, w1a[2*j2+0], fmaf(pos, w1b[2*j2+0], cfrag[2*j2+0])));
            const float hb = fast_tanh(fmaf(angl, w1a[2*j2+1], fmaf(pos, w1b[2*j2+1], cfrag[2*j2+1])));
            A.u[j2] = cvt_pk_bf16(ha, hb);
        }

        f32x4 acc0 = {b2c0, b2c0, b2c0, b2c0};
        f32x4 acc1 = {b2c1, b2c1, b2c1, b2c1};
        acc0 = __builtin_amdgcn_mfma_f32_16x16x32_bf16(A.s8, B0.s8, acc0, 0, 0, 0);
        acc1 = __builtin_amdgcn_mfma_f32_16x16x32_bf16(A.s8, B1.s8, acc1, 0, 0, 0);

        float lg[4];
        #pragma unroll
        for (int r = 0; r < 4; ++r)
            lg[r] = fmaf(fast_tanh(acc0[r]), w3c0, fast_tanh(acc1[r]) * w3c1);

        #pragma unroll
        for (int off = 1; off < 16; off <<= 1) {
            #pragma unroll
            for (int r = 0; r < 4; ++r) lg[r] += __shfl_xor(lg[r], off);
        }

        if (c15 == 0) {
            #pragma unroll
            for (int r = 0; r < 4; ++r) {
                const int idx = tile*16 + kg*4 + r;
                if (idx < M) slogc[idx] = lg[r] + b3v;
            }
        }
    }
    __syncthreads();

    // ---- pass 2: compacted softmax + aw @ coeff_values ----
    float m = -3.4e38f;
    if (M > 0)
        for (int i = t; i < M; i += 256) m = fmaxf(m, slogc[i]);
    #pragma unroll
    for (int off = 32; off; off >>= 1) m = fmaxf(m, __shfl_xor(m, off));
    if (lane == 0) sred[wid] = m;
    __syncthreads();
    m = fmaxf(fmaxf(sred[0], sred[1]), fmaxf(sred[2], sred[3]));

    float s = 0.0f, q0 = 0.0f, q1 = 0.0f;
    if (M > 0) {
        for (int i = t; i < M; i += 256) {
            const float e = EXP2((slogc[i] - m) * 1.44269504f);
            const float2 cvv = ((const float2*)cv)[slist[i]];
            s += e;
            q0 = fmaf(e, cvv.x, q0);
            q1 = fmaf(e, cvv.y, q1);
        }
    } else {   // all masked -> uniform softmax
        for (int i = t; i < PP; i += 256) {
            const float2 cvv = ((const float2*)cv)[i];
            s += 1.0f; q0 += cvv.x; q1 += cvv.y;
        }
    }
    #pragma unroll
    for (int off = 32; off; off >>= 1) {
        s  += __shfl_xor(s, off);
        q0 += __shfl_xor(q0, off);
        q1 += __shfl_xor(q1, off);
    }
    __syncthreads();
    if (lane == 0) {
        sred[4 + wid*3 + 0] = s;
        sred[4 + wid*3 + 1] = q0;
        sred[4 + wid*3 + 2] = q1;
    }
    __syncthreads();
    if (t == 0) {
        float S = 0.0f, Q0 = 0.0f, Q1 = 0.0f;
        #pragma unroll
        for (int w = 0; w < 4; ++w) {
            S  += sred[4 + w*3 + 0];
            Q0 += sred[4 + w*3 + 1];
            Q1 += sred[4 + w*3 + 2];
        }
        const float invS = fast_rcp(S);
        coeff_out[n*2+0] = __expf(-Q0 * invS);
        coeff_out[n*2+1] = __expf(-Q1 * invS);
    }
}

// ------- Kernel C: green MLP via MFMA. Block = 4 rows, wave = 1 row (80 slots) -------
__global__ __launch_bounds__(256) void green_kernel(
    const float* __restrict__ pc,  const float* __restrict__ bc,
    const float* __restrict__ skc, const float* __restrict__ sk,
    const float* __restrict__ vw,
    const float* __restrict__ gw1, const float* __restrict__ gb1,
    const float* __restrict__ gw2, const float* __restrict__ gb2,
    const float* __restrict__ gw3, const float* __restrict__ gb3,
    const float* __restrict__ rw,  const float* __restrict__ rb,
    const float* __restrict__ fw,  const float* __restrict__ fb,
    const float* __restrict__ coeff,
    float* __restrict__ out)
{
    __shared__ unsigned short sinA[GR_ROWS*GR_SLOTS*16]; // bf16 [320][16], k<10 used
    __shared__ unsigned short shb[4][16*64];             // per-wave h-tile, swizzled
    __shared__ float swq[GR_SLOTS];
    __shared__ float sg0[4][64];
    __shared__ float squad[4][64];

    const int t = threadIdx.x;
    const int w = t >> 6, lane = t & 63;
    const int c15 = lane & 15, kg = lane >> 4;
    const int n0 = blockIdx.x * GR_ROWS;

    // ---- weight fragments (per lane, loop-invariant) ----
    V4 Bw1[4], Bw2[2][4], Bw3[2][4];
    #pragma unroll
    for (int nt = 0; nt < 4; ++nt) {
        const int col = c15 + nt*16;
        #pragma unroll
        for (int j2 = 0; j2 < 4; ++j2) {
            const int ka = kg*8 + 2*j2, kb = ka + 1;
            const float va = (ka < 10) ? gw1[ka*64 + col] : 0.0f;
            const float vb = (kb < 10) ? gw1[kb*64 + col] : 0.0f;
            Bw1[nt].u[j2] = cvt_pk_bf16(va, vb);
        }
        #pragma unroll
        for (int kt = 0; kt < 2; ++kt) {
            #pragma unroll
            for (int j2 = 0; j2 < 4; ++j2) {
                const int ka = kt*32 + kg*8 + 2*j2, kb = ka + 1;
                Bw2[kt][nt].u[j2] = cvt_pk_bf16(gw2[ka*64 + col], gw2[kb*64 + col]);
                Bw3[kt][nt].u[j2] = cvt_pk_bf16(gw3[ka*64 + col], gw3[kb*64 + col]);
            }
        }
    }
    float b1c[4], b2c[4], b3c[4];
    #pragma unroll
    for (int nt = 0; nt < 4; ++nt) {
        b1c[nt] = gb1[c15 + nt*16];
        b2c[nt] = gb2[c15 + nt*16];
        b3c[nt] = gb3[c15 + nt*16];
    }

    // ---- G1: build bf16 input rows [4 rows x 80 slots][16] ----
    for (int row = t; row < GR_ROWS*GR_SLOTS; row += 256) {
        const int nl = row / GR_SLOTS;
        const int s  = row - nl*GR_SLOTS;
        const int n  = n0 + nl;
        u32x4 lo = {0u,0u,0u,0u}, hi = {0u,0u,0u,0u};
        if (s <= 64) {
            const float X0 = pc[n*4+0], X1 = pc[n*4+1];
            const float V0 = pc[n*4+2], V1 = pc[n*4+3];
            const float XP0 = bc[n*4+0], XP1 = bc[n*4+1];
            float I6, I7;
            if (s == 64) { I6 = bc[n*4+2]; I7 = bc[n*4+3]; }
            else         { I6 = skc[s*2+0]; I7 = skc[s*2+1]; }
            const float C0 = coeff[n*2+0], C1 = coeff[n*2+1];
            lo[0] = cvt_pk_bf16(X0, X1);
            lo[1] = cvt_pk_bf16(V0, V1);
            lo[2] = cvt_pk_bf16(XP0, XP1);
            lo[3] = cvt_pk_bf16(I6, I7);
            hi[0] = cvt_pk_bf16(C0, C1);
        }
        ((u32x4*)sinA)[row*2 + 0] = lo;
        ((u32x4*)sinA)[row*2 + 1] = hi;
    }
    if (t < GR_SLOTS)
        swq[t] = (t < QQ) ? (1.0f - sk[t]) * vw[t] : 0.0f;
    __syncthreads();

    // ---- G2: per wave, 5 M-tiles of its row ----
    unsigned short* hb = &shb[w][0];
    float qacc[4] = {0.f, 0.f, 0.f, 0.f};

    #pragma unroll 1
    for (int T = 0; T < GR_MT; ++T) {
        const int rm = w*GR_SLOTS + T*16 + c15;
        // layer-1 A-frag (K=32, k>=16 zero)
        V4 A1; A1.u = (u32x4){0u,0u,0u,0u};
        if (kg < 2) A1.u = ((u32x4*)sinA)[rm*2 + kg];

        f32x4 acc1[4];
        #pragma unroll
        for (int nt = 0; nt < 4; ++nt) {
            f32x4 a = {b1c[nt], b1c[nt], b1c[nt], b1c[nt]};
            acc1[nt] = __builtin_amdgcn_mfma_f32_16x16x32_bf16(A1.s, Bw1[nt].s, a, 0, 0, 0);
        }
        // tanh + store to wave-private swizzled h-tile
        #pragma unroll
        for (int nt = 0; nt < 4; ++nt) {
            #pragma unroll
            for (int r = 0; r < 4; ++r) {
                const int rl = kg*4 + r;
                hb[rl*64 + ((c15 + nt*16) ^ ((rl&7)<<3))] = bf16_bits(fast_tanh(acc1[nt][r]));
            }
        }
        // layer-2
        V4 A2[2];
        #pragma unroll
        for (int kt = 0; kt < 2; ++kt)
            A2[kt].u = ((u32x4*)hb)[(c15*64 + ((kt*32 + kg*8) ^ ((c15&7)<<3))) >> 3];
        f32x4 acc2[4];
        #pragma unroll
        for (int nt = 0; nt < 4; ++nt) {
            f32x4 a = {b2c[nt], b2c[nt], b2c[nt], b2c[nt]};
            a = __builtin_amdgcn_mfma_f32_16x16x32_bf16(A2[0].s, Bw2[0][nt].s, a, 0, 0, 0);
            acc2[nt] = __builtin_amdgcn_mfma_f32_16x16x32_bf16(A2[1].s, Bw2[1][nt].s, a, 0, 0, 0);
        }
        #pragma unroll
        for (int nt = 0; nt < 4; ++nt) {
            #pragma unroll
            for (int r = 0; r < 4; ++r) {
                const int rl = kg*4 + r;
                hb[rl*64 + ((c15 + nt*16) ^ ((rl&7)<<3))] = bf16_bits(fast_tanh(acc2[nt][r]));
            }
        }
        // layer-3
        V4 A3[2];
        #pragma unroll
        for (int kt = 0; kt < 2; ++kt)
            A3[kt].u = ((u32x4*)hb)[(c15*64 + ((kt*32 + kg*8) ^ ((c15&7)<<3))) >> 3];
        f32x4 acc3[4];
        #pragma unroll
        for (int nt = 0; nt < 4; ++nt) {
            f32x4 a = {b3c[nt], b3c[nt], b3c[nt], b3c[nt]};
            a = __builtin_amdgcn_mfma_f32_16x16x32_bf16(A3[0].s, Bw3[0][nt].s, a, 0, 0, 0);
            acc3[nt] = __builtin_amdgcn_mfma_f32_16x16x32_bf16(A3[1].s, Bw3[1][nt].s, a, 0, 0, 0);
        }
        // g = exp(tanh(.)), quad accumulate + g0 capture
        #pragma unroll
        for (int r = 0; r < 4; ++r) {
            const int s = T*16 + kg*4 + r;
            const float wq = swq[s];
            #pragma unroll
            for (int nt = 0; nt < 4; ++nt) {
                const float g = __expf(fast_tanh(acc3[nt][r]));
                qacc[nt] = fmaf(wq, g, qacc[nt]);
                if (T == GR_MT-1 && kg == 0 && r == 0) sg0[w][c15 + nt*16] = g;
            }
        }
    }

    // reduce quad over kg groups (wave-private)
    #pragma unroll
    for (int nt = 0; nt < 4; ++nt) {
        qacc[nt] += __shfl_xor(qacc[nt], 16);
        qacc[nt] += __shfl_xor(qacc[nt], 32);
    }
    if (kg == 0) {
        #pragma unroll
        for (int nt = 0; nt < 4; ++nt) squad[w][c15 + nt*16] = qacc[nt];
    }

    // ---- G3: res + final (wave-private) ----
    const int k = lane;
    float r0a = rb[k], r1a = 0.f, r2a = 0.f, r3a = 0.f;
    #pragma unroll
    for (int j = 0; j < 64; j += 4) {
        const float4 qd = *(const float4*)&squad[w][j];
        r0a = fmaf(qd.x, rw[(j+0)*64 + k], r0a);
        r1a = fmaf(qd.y, rw[(j+1)*64 + k], r1a);
        r2a = fmaf(qd.z, rw[(j+2)*64 + k], r2a);
        r3a = fmaf(qd.w, rw[(j+3)*64 + k], r3a);
    }
    const float resv = fast_tanh((r0a + r1a) + (r2a + r3a));
    float term = (sg0[w][k] + resv) * fw[k];
    #pragma unroll
    for (int off = 32; off; off >>= 1) term += __shfl_xor(term, off);
    if (lane == 0) out[n0 + w] = term + fb[0];
}

extern "C" void kernel_launch(void* const* d_in, const int* in_sizes, int n_in,
                              void* d_out, int out_size, void* d_ws, size_t ws_size,
                              hipStream_t stream) {
    const float* pc  = (const float*)d_in[0];
    const float* bc  = (const float*)d_in[1];
    const float* cp  = (const float*)d_in[2];
    const float* cv  = (const float*)d_in[3];
    const float* skc = (const float*)d_in[4];
    const float* sk  = (const float*)d_in[5];
    const float* vw  = (const float*)d_in[6];
    const float* aw1 = (const float*)d_in[7];
    const float* ab1 = (const float*)d_in[8];
    const float* aw2 = (const float*)d_in[9];
    const float* ab2 = (const float*)d_in[10];
    const float* aw3 = (const float*)d_in[11];
    const float* ab3 = (const float*)d_in[12];
    const float* gw1 = (const float*)d_in[13];
    const float* gb1 = (const float*)d_in[14];
    const float* gw2 = (const float*)d_in[15];
    const float* gb2 = (const float*)d_in[16];
    const float* gw3 = (const float*)d_in[17];
    const float* gb3 = (const float*)d_in[18];
    const float* rw  = (const float*)d_in[19];
    const float* rb  = (const float*)d_in[20];
    const float* fw  = (const float*)d_in[21];
    const float* fb  = (const float*)d_in[22];

    float* coeff = (float*)d_ws;          // N*2 floats
    float* outp  = (float*)d_out;

    attn_kernel<<<NN, 256, 0, stream>>>(pc, cp, cv, aw1, ab1, aw2, ab2, aw3, ab3, coeff);
    green_kernel<<<NN/GR_ROWS, 256, 0, stream>>>(pc, bc, skc, sk, vw,
                                                 gw1, gb1, gw2, gb2, gw3, gb3,
                                                 rw, rb, fw, fb, coeff, outp);
}

// Round 8
// 90.134 us; speedup vs baseline: 4.2558x; 1.1215x over previous
//
#include <hip/hip_runtime.h>

#define NN 2048
#define PP 2048
#define QQ 64
#define GR_ROWS 4
#define GR_SLOTS 80   // 64 quad + g0(slot 64) + 15 pad
#define GR_MT 5       // 16-row M-tiles per row

typedef __attribute__((ext_vector_type(8))) short short8;
typedef __attribute__((ext_vector_type(4))) float f32x4;
typedef __attribute__((ext_vector_type(4))) unsigned u32x4;

union V4 { u32x4 u; short8 s; };

#if __has_builtin(__builtin_amdgcn_exp2f)
#define EXP2(x) __builtin_amdgcn_exp2f(x)
#else
#define EXP2(x) exp2f(x)
#endif

__device__ __forceinline__ float fast_rcp(float x) { return __builtin_amdgcn_rcpf(x); }

// tanh(x) = 1 - 2/(2^(2x*log2e)+1); saturates for |x| large (rcp(inf)=0)
__device__ __forceinline__ float fast_tanh(float x) {
    float t = EXP2(x * 2.885390082f);
    return 1.0f - 2.0f * __builtin_amdgcn_rcpf(t + 1.0f);
}

// packed f32x2 -> bf16x2 (RNE), single instruction
__device__ __forceinline__ unsigned cvt_pk_bf16(float lo, float hi) {
    unsigned r;
    asm("v_cvt_pk_bf16_f32 %0, %1, %2" : "=v"(r) : "v"(lo), "v"(hi));
    return r;
}
// scalar RNE bf16 bits (for single stores)
__device__ __forceinline__ unsigned short bf16_bits(float f) {
    unsigned u = __builtin_bit_cast(unsigned, f);
    u += 0x7FFFu + ((u >> 16) & 1u);
    return (unsigned short)(u >> 16);
}

// ---- Kernel A: block = one row; cp staged in LDS; transposed-MFMA layer2 ----
__global__ __launch_bounds__(256) void attn_kernel(
    const float* __restrict__ pc, const float* __restrict__ cp,
    const float* __restrict__ cv,
    const float* __restrict__ w1, const float* __restrict__ b1,
    const float* __restrict__ w2, const float* __restrict__ b2,
    const float* __restrict__ w3, const float* __restrict__ b3,
    float* __restrict__ coeff_out)
{
    __shared__ float2 scp[PP];           // coeff_position staged (16 KB)
    __shared__ float slogc[PP];          // compacted logits
    __shared__ unsigned short slist[PP]; // compacted p-indices
    __shared__ float sred[16];
    __shared__ int scount;

    const int n = blockIdx.x;
    const int t = threadIdx.x;
    const int wid  = t >> 6;
    const int lane = t & 63;
    const int c15  = lane & 15;
    const int kg   = lane >> 4;
    const int k0   = kg * 8;

    const float b3v = b3[0];

    // stage cp -> LDS (row-invariant)
    #pragma unroll
    for (int i = 0; i < PP/256; ++i)
        scp[i*256 + t] = ((const float2*)cp)[i*256 + t];
    if (t == 0) scount = 0;

    const float x0 = pc[n*4+0], x1 = pc[n*4+1];
    const float v0 = pc[n*4+2], v1 = pc[n*4+3];
    const float rinv = __builtin_amdgcn_rsqf(v0*v0 + v1*v1 + 1e-16f);
    const float a0 = v0 * rinv, a1 = v1 * rinv;

    // ---- row-invariant fragments ----
    // A-operand for transposed MFMA: w2 columns (w2^T rows)
    union BF { short8 s8; unsigned u[4]; } B0, B1;
    #pragma unroll
    for (int j2 = 0; j2 < 4; ++j2) {
        const int ka = k0 + 2*j2, kb = ka + 1;
        B0.u[j2] = cvt_pk_bf16(w2[ka*32 + c15],      w2[kb*32 + c15]);
        B1.u[j2] = cvt_pk_bf16(w2[ka*32 + c15 + 16], w2[kb*32 + c15 + 16]);
    }
    // transposed-D per-lane rows: neuron = kg*4+r (acca) and 16+kg*4+r (accb)
    float b2a[4], b2b[4], w3a[4], w3b[4];
    #pragma unroll
    for (int r = 0; r < 4; ++r) {
        b2a[r] = b2[kg*4 + r];      b2b[r] = b2[16 + kg*4 + r];
        w3a[r] = w3[kg*4 + r];      w3b[r] = w3[16 + kg*4 + r];
    }
    // layer-1: per-lane k-slice constants
    float cfrag[8], w1a[8], w1b[8];
    #pragma unroll
    for (int j = 0; j < 8; ++j) {
        const int k = k0 + j;
        float c = b1[k];
        c = fmaf(x0, w1[0*32+k], c);
        c = fmaf(x1, w1[1*32+k], c);
        c = fmaf(v0, w1[2*32+k], c);
        c = fmaf(v1, w1[3*32+k], c);
        cfrag[j] = c;
        w1a[j] = w1[4*32+k];
        w1b[j] = w1[5*32+k];
    }
    __syncthreads();   // scp + scount ready

    // ---- pass 0: compact unmasked p (reads scp) ----
    #pragma unroll 1
    for (int i = 0; i < PP/256; ++i) {
        const int p = i*256 + t;
        const float2 cpp = scp[p];
        const float pos = fmaf(x0 - cpp.x, a0, (x1 - cpp.y) * a1);
        const bool f = pos > 0.0f;
        const unsigned long long mask = __ballot(f);
        int base = 0;
        if (lane == 0 && mask) base = atomicAdd(&scount, __popcll(mask));
        base = __shfl(base, 0);
        if (f) {
            const int idx = base + __popcll(mask & ((1ull << lane) - 1ull));
            slist[idx] = (unsigned short)p;
        }
    }
    __syncthreads();
    const int M  = scount;
    const int Mt = (M + 15) >> 4;

    // ---- pass 1: logits for survivors (transposed layer-2 MFMA) ----
    #pragma unroll 2
    for (int tile = wid; tile < Mt; tile += 4) {
        const int li = tile*16 + c15;
        const int p  = slist[li < M ? li : 0];
        const float2 cpp = scp[p];
        const float r0 = x0 - cpp.x;
        const float r1 = x1 - cpp.y;
        const float dist = sqrtf(r0*r0 + r1*r1 + 1e-16f);
        const float pos  = fmaf(r0, a0, r1*a1);
        const float angl = pos * fast_rcp(dist + 1e-8f);

        // h1 for pair c15, neurons k0..k0+7 (B-operand = h1^T)
        union AF { short8 s8; unsigned u[4]; } H;
        #pragma unroll
        for (int j2 = 0; j2 < 4; ++j2) {
            const float ha = fast_tanh(fmaf(angl, w1a[2*j2+0], fmaf(pos, w1b[2*j2+0], cfrag[2*j2+0])));
            const float hb = fast_tanh(fmaf(angl, w1a[2*j2+1], fmaf(pos, w1b[2*j2+1], cfrag[2*j2+1])));
            H.u[j2] = cvt_pk_bf16(ha, hb);
        }

        // D = W2^T · H1^T : col = pair (c15), row = neuron (kg*4+r)
        f32x4 acca = {b2a[0], b2a[1], b2a[2], b2a[3]};
        f32x4 accb = {b2b[0], b2b[1], b2b[2], b2b[3]};
        acca = __builtin_amdgcn_mfma_f32_16x16x32_bf16(B0.s8, H.s8, acca, 0, 0, 0);
        accb = __builtin_amdgcn_mfma_f32_16x16x32_bf16(B1.s8, H.s8, accb, 0, 0, 0);

        // partial logit for pair c15 (8 of 32 neurons) then 2-shuffle reduce over kg
        float lg = 0.0f;
        #pragma unroll
        for (int r = 0; r < 4; ++r) {
            lg = fmaf(fast_tanh(acca[r]), w3a[r], lg);
            lg = fmaf(fast_tanh(accb[r]), w3b[r], lg);
        }
        lg += __shfl_xor(lg, 16);
        lg += __shfl_xor(lg, 32);

        const int idx = tile*16 + c15;
        if (kg == 0 && idx < M) slogc[idx] = lg + b3v;
    }
    __syncthreads();

    // ---- pass 2: compacted softmax + aw @ coeff_values ----
    float m = -3.4e38f;
    if (M > 0)
        for (int i = t; i < M; i += 256) m = fmaxf(m, slogc[i]);
    #pragma unroll
    for (int off = 32; off; off >>= 1) m = fmaxf(m, __shfl_xor(m, off));
    if (lane == 0) sred[wid] = m;
    __syncthreads();
    m = fmaxf(fmaxf(sred[0], sred[1]), fmaxf(sred[2], sred[3]));

    float s = 0.0f, q0 = 0.0f, q1 = 0.0f;
    if (M > 0) {
        #pragma unroll 2
        for (int i = t; i < M; i += 256) {
            const float e = EXP2((slogc[i] - m) * 1.44269504f);
            const float2 cvv = ((const float2*)cv)[slist[i]];
            s += e;
            q0 = fmaf(e, cvv.x, q0);
            q1 = fmaf(e, cvv.y, q1);
        }
    } else {   // all masked -> uniform softmax
        for (int i = t; i < PP; i += 256) {
            const float2 cvv = ((const float2*)cv)[i];
            s += 1.0f; q0 += cvv.x; q1 += cvv.y;
        }
    }
    #pragma unroll
    for (int off = 32; off; off >>= 1) {
        s  += __shfl_xor(s, off);
        q0 += __shfl_xor(q0, off);
        q1 += __shfl_xor(q1, off);
    }
    __syncthreads();
    if (lane == 0) {
        sred[4 + wid*3 + 0] = s;
        sred[4 + wid*3 + 1] = q0;
        sred[4 + wid*3 + 2] = q1;
    }
    __syncthreads();
    if (t == 0) {
        float S = 0.0f, Q0 = 0.0f, Q1 = 0.0f;
        #pragma unroll
        for (int w = 0; w < 4; ++w) {
            S  += sred[4 + w*3 + 0];
            Q0 += sred[4 + w*3 + 1];
            Q1 += sred[4 + w*3 + 2];
        }
        const float invS = fast_rcp(S);
        coeff_out[n*2+0] = __expf(-Q0 * invS);
        coeff_out[n*2+1] = __expf(-Q1 * invS);
    }
}

// ------- Kernel C: green MLP via MFMA. Block = 4 rows, wave = 1 row (80 slots) -------
__global__ __launch_bounds__(256) void green_kernel(
    const float* __restrict__ pc,  const float* __restrict__ bc,
    const float* __restrict__ skc, const float* __restrict__ sk,
    const float* __restrict__ vw,
    const float* __restrict__ gw1, const float* __restrict__ gb1,
    const float* __restrict__ gw2, const float* __restrict__ gb2,
    const float* __restrict__ gw3, const float* __restrict__ gb3,
    const float* __restrict__ rw,  const float* __restrict__ rb,
    const float* __restrict__ fw,  const float* __restrict__ fb,
    const float* __restrict__ coeff,
    float* __restrict__ out)
{
    __shared__ unsigned short sinA[GR_ROWS*GR_SLOTS*16]; // bf16 [320][16], k<10 used
    __shared__ unsigned short shb[4][16*64];             // per-wave h-tile, swizzled
    __shared__ float swq[GR_SLOTS];
    __shared__ float sg0[4][64];
    __shared__ float squad[4][64];

    const int t = threadIdx.x;
    const int w = t >> 6, lane = t & 63;
    const int c15 = lane & 15, kg = lane >> 4;
    const int n0 = blockIdx.x * GR_ROWS;

    // ---- weight fragments (per lane, loop-invariant) ----
    V4 Bw1[4], Bw2[2][4], Bw3[2][4];
    #pragma unroll
    for (int nt = 0; nt < 4; ++nt) {
        const int col = c15 + nt*16;
        #pragma unroll
        for (int j2 = 0; j2 < 4; ++j2) {
            const int ka = kg*8 + 2*j2, kb = ka + 1;
            const float va = (ka < 10) ? gw1[ka*64 + col] : 0.0f;
            const float vb = (kb < 10) ? gw1[kb*64 + col] : 0.0f;
            Bw1[nt].u[j2] = cvt_pk_bf16(va, vb);
        }
        #pragma unroll
        for (int kt = 0; kt < 2; ++kt) {
            #pragma unroll
            for (int j2 = 0; j2 < 4; ++j2) {
                const int ka = kt*32 + kg*8 + 2*j2, kb = ka + 1;
                Bw2[kt][nt].u[j2] = cvt_pk_bf16(gw2[ka*64 + col], gw2[kb*64 + col]);
                Bw3[kt][nt].u[j2] = cvt_pk_bf16(gw3[ka*64 + col], gw3[kb*64 + col]);
            }
        }
    }
    float b1c[4], b2c[4], b3c[4];
    #pragma unroll
    for (int nt = 0; nt < 4; ++nt) {
        b1c[nt] = gb1[c15 + nt*16];
        b2c[nt] = gb2[c15 + nt*16];
        b3c[nt] = gb3[c15 + nt*16];
    }

    // ---- G1: build bf16 input rows [4 rows x 80 slots][16] ----
    for (int row = t; row < GR_ROWS*GR_SLOTS; row += 256) {
        const int nl = row / GR_SLOTS;
        const int s  = row - nl*GR_SLOTS;
        const int n  = n0 + nl;
        u32x4 lo = {0u,0u,0u,0u}, hi = {0u,0u,0u,0u};
        if (s <= 64) {
            const float X0 = pc[n*4+0], X1 = pc[n*4+1];
            const float V0 = pc[n*4+2], V1 = pc[n*4+3];
            const float XP0 = bc[n*4+0], XP1 = bc[n*4+1];
            float I6, I7;
            if (s == 64) { I6 = bc[n*4+2]; I7 = bc[n*4+3]; }
            else         { I6 = skc[s*2+0]; I7 = skc[s*2+1]; }
            const float C0 = coeff[n*2+0], C1 = coeff[n*2+1];
            lo[0] = cvt_pk_bf16(X0, X1);
            lo[1] = cvt_pk_bf16(V0, V1);
            lo[2] = cvt_pk_bf16(XP0, XP1);
            lo[3] = cvt_pk_bf16(I6, I7);
            hi[0] = cvt_pk_bf16(C0, C1);
        }
        ((u32x4*)sinA)[row*2 + 0] = lo;
        ((u32x4*)sinA)[row*2 + 1] = hi;
    }
    if (t < GR_SLOTS)
        swq[t] = (t < QQ) ? (1.0f - sk[t]) * vw[t] : 0.0f;
    __syncthreads();

    // ---- G2: per wave, 5 M-tiles of its row ----
    unsigned short* hb = &shb[w][0];
    float qacc[4] = {0.f, 0.f, 0.f, 0.f};

    #pragma unroll 1
    for (int T = 0; T < GR_MT; ++T) {
        const int rm = w*GR_SLOTS + T*16 + c15;
        // layer-1 A-frag (K=32, k>=16 zero)
        V4 A1; A1.u = (u32x4){0u,0u,0u,0u};
        if (kg < 2) A1.u = ((u32x4*)sinA)[rm*2 + kg];

        f32x4 acc1[4];
        #pragma unroll
        for (int nt = 0; nt < 4; ++nt) {
            f32x4 a = {b1c[nt], b1c[nt], b1c[nt], b1c[nt]};
            acc1[nt] = __builtin_amdgcn_mfma_f32_16x16x32_bf16(A1.s, Bw1[nt].s, a, 0, 0, 0);
        }
        // tanh + store to wave-private swizzled h-tile
        #pragma unroll
        for (int nt = 0; nt < 4; ++nt) {
            #pragma unroll
            for (int r = 0; r < 4; ++r) {
                const int rl = kg*4 + r;
                hb[rl*64 + ((c15 + nt*16) ^ ((rl&7)<<3))] = bf16_bits(fast_tanh(acc1[nt][r]));
            }
        }
        // layer-2
        V4 A2[2];
        #pragma unroll
        for (int kt = 0; kt < 2; ++kt)
            A2[kt].u = ((u32x4*)hb)[(c15*64 + ((kt*32 + kg*8) ^ ((c15&7)<<3))) >> 3];
        f32x4 acc2[4];
        #pragma unroll
        for (int nt = 0; nt < 4; ++nt) {
            f32x4 a = {b2c[nt], b2c[nt], b2c[nt], b2c[nt]};
            a = __builtin_amdgcn_mfma_f32_16x16x32_bf16(A2[0].s, Bw2[0][nt].s, a, 0, 0, 0);
            acc2[nt] = __builtin_amdgcn_mfma_f32_16x16x32_bf16(A2[1].s, Bw2[1][nt].s, a, 0, 0, 0);
        }
        #pragma unroll
        for (int nt = 0; nt < 4; ++nt) {
            #pragma unroll
            for (int r = 0; r < 4; ++r) {
                const int rl = kg*4 + r;
                hb[rl*64 + ((c15 + nt*16) ^ ((rl&7)<<3))] = bf16_bits(fast_tanh(acc2[nt][r]));
            }
        }
        // layer-3
        V4 A3[2];
        #pragma unroll
        for (int kt = 0; kt < 2; ++kt)
            A3[kt].u = ((u32x4*)hb)[(c15*64 + ((kt*32 + kg*8) ^ ((c15&7)<<3))) >> 3];
        f32x4 acc3[4];
        #pragma unroll
        for (int nt = 0; nt < 4; ++nt) {
            f32x4 a = {b3c[nt], b3c[nt], b3c[nt], b3c[nt]};
            a = __builtin_amdgcn_mfma_f32_16x16x32_bf16(A3[0].s, Bw3[0][nt].s, a, 0, 0, 0);
            acc3[nt] = __builtin_amdgcn_mfma_f32_16x16x32_bf16(A3[1].s, Bw3[1][nt].s, a, 0, 0, 0);
        }
        // g = exp(tanh(.)), quad accumulate + g0 capture
        #pragma unroll
        for (int r = 0; r < 4; ++r) {
            const int s = T*16 + kg*4 + r;
            const float wq = swq[s];
            #pragma unroll
            for (int nt = 0; nt < 4; ++nt) {
                const float g = __expf(fast_tanh(acc3[nt][r]));
                qacc[nt] = fmaf(wq, g, qacc[nt]);
                if (T == GR_MT-1 && kg == 0 && r == 0) sg0[w][c15 + nt*16] = g;
            }
        }
    }

    // reduce quad over kg groups (wave-private)
    #pragma unroll
    for (int nt = 0; nt < 4; ++nt) {
        qacc[nt] += __shfl_xor(qacc[nt], 16);
        qacc[nt] += __shfl_xor(qacc[nt], 32);
    }
    if (kg == 0) {
        #pragma unroll
        for (int nt = 0; nt < 4; ++nt) squad[w][c15 + nt*16] = qacc[nt];
    }

    // ---- G3: res + final (wave-private) ----
    const int k = lane;
    float r0a = rb[k], r1a = 0.f, r2a = 0.f, r3a = 0.f;
    #pragma unroll
    for (int j = 0; j < 64; j += 4) {
        const float4 qd = *(const float4*)&squad[w][j];
        r0a = fmaf(qd.x, rw[(j+0)*64 + k], r0a);
        r1a = fmaf(qd.y, rw[(j+1)*64 + k], r1a);
        r2a = fmaf(qd.z, rw[(j+2)*64 + k], r2a);
        r3a = fmaf(qd.w, rw[(j+3)*64 + k], r3a);
    }
    const float resv = fast_tanh((r0a + r1a) + (r2a + r3a));
    float term = (sg0[w][k] + resv) * fw[k];
    #pragma unroll
    for (int off = 32; off; off >>= 1) term += __shfl_xor(term, off);
    if (lane == 0) out[n0 + w] = term + fb[0];
}

extern "C" void kernel_launch(void* const* d_in, const int* in_sizes, int n_in,
                              void* d_out, int out_size, void* d_ws, size_t ws_size,
                              hipStream_t stream) {
    const float* pc  = (const float*)d_in[0];
    const float* bc  = (const float*)d_in[1];
    const float* cp  = (const float*)d_in[2];
    const float* cv  = (const float*)d_in[3];
    const float* skc = (const float*)d_in[4];
    const float* sk  = (const float*)d_in[5];
    const float* vw  = (const float*)d_in[6];
    const float* aw1 = (const float*)d_in[7];
    const float* ab1 = (const float*)d_in[8];
    const float* aw2 = (const float*)d_in[9];
    const float* ab2 = (const float*)d_in[10];
    const float* aw3 = (const float*)d_in[11];
    const float* ab3 = (const float*)d_in[12];
    const float* gw1 = (const float*)d_in[13];
    const float* gb1 = (const float*)d_in[14];
    const float* gw2 = (const float*)d_in[15];
    const float* gb2 = (const float*)d_in[16];
    const float* gw3 = (const float*)d_in[17];
    const float* gb3 = (const float*)d_in[18];
    const float* rw  = (const float*)d_in[19];
    const float* rb  = (const float*)d_in[20];
    const float* fw  = (const float*)d_in[21];
    const float* fb  = (const float*)d_in[22];

    float* coeff = (float*)d_ws;          // N*2 floats = 16 KB (known-safe)
    float* outp  = (float*)d_out;

    attn_kernel<<<NN, 256, 0, stream>>>(pc, cp, cv, aw1, ab1, aw2, ab2, aw3, ab3, coeff);
    green_kernel<<<NN/GR_ROWS, 256, 0, stream>>>(pc, bc, skc, sk, vw,
                                                 gw1, gb1, gw2, gb2, gw3, gb3,
                                                 rw, rb, fw, fb, coeff, outp);
}

// Round 9
// 84.240 us; speedup vs baseline: 4.5535x; 1.0700x over previous
//
#include <hip/hip_runtime.h>

#define NN 2048
#define PP 2048
#define QQ 64
#define GR_ROWS 4
#define GR_SLOTS 80   // 64 quad + g0(slot 64) + 15 pad
#define GR_MT 5       // 16-row M-tiles per row

typedef __attribute__((ext_vector_type(8))) short short8;
typedef __attribute__((ext_vector_type(4))) float f32x4;
typedef __attribute__((ext_vector_type(4))) unsigned u32x4;

union V4 { u32x4 u; short8 s; };

#if __has_builtin(__builtin_amdgcn_exp2f)
#define EXP2(x) __builtin_amdgcn_exp2f(x)
#else
#define EXP2(x) exp2f(x)
#endif

__device__ __forceinline__ float fast_rcp(float x) { return __builtin_amdgcn_rcpf(x); }

// tanh(x) = 1 - 2/(2^(2x*log2e)+1); saturates for |x| large (rcp(inf)=0)
__device__ __forceinline__ float fast_tanh(float x) {
    float t = EXP2(x * 2.885390082f);
    return 1.0f - 2.0f * __builtin_amdgcn_rcpf(t + 1.0f);
}

// packed f32x2 -> bf16x2 (RNE), single instruction
__device__ __forceinline__ unsigned cvt_pk_bf16(float lo, float hi) {
    unsigned r;
    asm("v_cvt_pk_bf16_f32 %0, %1, %2" : "=v"(r) : "v"(lo), "v"(hi));
    return r;
}
// scalar RNE bf16 bits (for single stores)
__device__ __forceinline__ unsigned short bf16_bits(float f) {
    unsigned u = __builtin_bit_cast(unsigned, f);
    u += 0x7FFFu + ((u >> 16) & 1u);
    return (unsigned short)(u >> 16);
}

// ---- Kernel A: compacted (angl,pos) in LDS; conflict-free pass1; transposed MFMA ----
__global__ __launch_bounds__(256) void attn_kernel(
    const float* __restrict__ pc, const float* __restrict__ cp,
    const float* __restrict__ cv,
    const float* __restrict__ w1, const float* __restrict__ b1,
    const float* __restrict__ w2, const float* __restrict__ b2,
    const float* __restrict__ w3, const float* __restrict__ b3,
    float* __restrict__ coeff_out)
{
    __shared__ float2 scpc[PP];          // compacted (angl,pos); .x overwritten by logit
    __shared__ unsigned short slist[PP]; // compacted p-indices
    __shared__ float sred[16];
    __shared__ int scount;

    const int n = blockIdx.x;
    const int t = threadIdx.x;
    const int wid  = t >> 6;
    const int lane = t & 63;
    const int c15  = lane & 15;
    const int kg   = lane >> 4;
    const int k0   = kg * 8;

    const float b3v = b3[0];

    if (t == 0) scount = 0;

    const float x0 = pc[n*4+0], x1 = pc[n*4+1];
    const float v0 = pc[n*4+2], v1 = pc[n*4+3];
    const float rinv = __builtin_amdgcn_rsqf(v0*v0 + v1*v1 + 1e-16f);
    const float a0 = v0 * rinv, a1 = v1 * rinv;

    // ---- row-invariant fragments ----
    // A-operand for transposed MFMA: w2 columns (w2^T rows)
    union BF { short8 s8; unsigned u[4]; } B0, B1;
    #pragma unroll
    for (int j2 = 0; j2 < 4; ++j2) {
        const int ka = k0 + 2*j2, kb = ka + 1;
        B0.u[j2] = cvt_pk_bf16(w2[ka*32 + c15],      w2[kb*32 + c15]);
        B1.u[j2] = cvt_pk_bf16(w2[ka*32 + c15 + 16], w2[kb*32 + c15 + 16]);
    }
    // transposed-D per-lane rows: neuron = kg*4+r (acca) and 16+kg*4+r (accb)
    float b2a[4], b2b[4], w3a[4], w3b[4];
    #pragma unroll
    for (int r = 0; r < 4; ++r) {
        b2a[r] = b2[kg*4 + r];      b2b[r] = b2[16 + kg*4 + r];
        w3a[r] = w3[kg*4 + r];      w3b[r] = w3[16 + kg*4 + r];
    }
    // layer-1: per-lane k-slice constants
    float cfrag[8], w1a[8], w1b[8];
    #pragma unroll
    for (int j = 0; j < 8; ++j) {
        const int k = k0 + j;
        float c = b1[k];
        c = fmaf(x0, w1[0*32+k], c);
        c = fmaf(x1, w1[1*32+k], c);
        c = fmaf(v0, w1[2*32+k], c);
        c = fmaf(v1, w1[3*32+k], c);
        cfrag[j] = c;
        w1a[j] = w1[4*32+k];
        w1b[j] = w1[5*32+k];
    }
    __syncthreads();   // scount ready

    // ---- pass 0: compact survivors, store (angl,pos) + p ----
    #pragma unroll 1
    for (int i = 0; i < PP/256; ++i) {
        const int p = i*256 + t;
        const float2 cpp = ((const float2*)cp)[p];
        const float r0 = x0 - cpp.x;
        const float r1 = x1 - cpp.y;
        const float pos = fmaf(r0, a0, r1*a1);
        const bool f = pos > 0.0f;
        const unsigned long long mask = __ballot(f);
        int base = 0;
        if (lane == 0 && mask) base = atomicAdd(&scount, __popcll(mask));
        base = __shfl(base, 0);
        if (f) {
            const int idx = base + __popcll(mask & ((1ull << lane) - 1ull));
            const float dist = sqrtf(r0*r0 + r1*r1 + 1e-16f);
            const float angl = pos * fast_rcp(dist + 1e-8f);
            slist[idx] = (unsigned short)p;
            scpc[idx] = make_float2(angl, pos);
        }
    }
    __syncthreads();
    const int M  = scount;
    const int Mt = (M + 15) >> 4;

    // ---- pass 1: logits for survivors (conflict-free broadcast reads) ----
    #pragma unroll 2
    for (int tile = wid; tile < Mt; tile += 4) {
        const int li = tile*16 + c15;
        const float2 ap = scpc[li < M ? li : 0];
        const float angl = ap.x, pos = ap.y;

        // h1 for pair c15, neurons k0..k0+7 (B-operand = h1^T)
        union AF { short8 s8; unsigned u[4]; } H;
        #pragma unroll
        for (int j2 = 0; j2 < 4; ++j2) {
            const float ha = fast_tanh(fmaf(angl, w1a[2*j2+0], fmaf(pos, w1b[2*j2+0], cfrag[2*j2+0])));
            const float hb = fast_tanh(fmaf(angl, w1a[2*j2+1], fmaf(pos, w1b[2*j2+1], cfrag[2*j2+1])));
            H.u[j2] = cvt_pk_bf16(ha, hb);
        }

        // D = W2^T · H1^T : col = pair (c15), row = neuron (kg*4+r)
        f32x4 acca = {b2a[0], b2a[1], b2a[2], b2a[3]};
        f32x4 accb = {b2b[0], b2b[1], b2b[2], b2b[3]};
        acca = __builtin_amdgcn_mfma_f32_16x16x32_bf16(B0.s8, H.s8, acca, 0, 0, 0);
        accb = __builtin_amdgcn_mfma_f32_16x16x32_bf16(B1.s8, H.s8, accb, 0, 0, 0);

        // partial logit for pair c15 (8 of 32 neurons) then 2-shuffle reduce over kg
        float lg = 0.0f;
        #pragma unroll
        for (int r = 0; r < 4; ++r) {
            lg = fmaf(fast_tanh(acca[r]), w3a[r], lg);
            lg = fmaf(fast_tanh(accb[r]), w3b[r], lg);
        }
        lg += __shfl_xor(lg, 16);
        lg += __shfl_xor(lg, 32);

        // overwrite angl slot with logit: tile-local indices, read already done
        if (kg == 0 && li < M) scpc[li].x = lg + b3v;
    }
    __syncthreads();

    // ---- pass 2: compacted softmax + aw @ coeff_values ----
    float m = -3.4e38f;
    if (M > 0)
        for (int i = t; i < M; i += 256) m = fmaxf(m, scpc[i].x);
    #pragma unroll
    for (int off = 32; off; off >>= 1) m = fmaxf(m, __shfl_xor(m, off));
    if (lane == 0) sred[wid] = m;
    __syncthreads();
    m = fmaxf(fmaxf(sred[0], sred[1]), fmaxf(sred[2], sred[3]));

    float s = 0.0f, q0 = 0.0f, q1 = 0.0f;
    if (M > 0) {
        #pragma unroll 2
        for (int i = t; i < M; i += 256) {
            const float e = EXP2((scpc[i].x - m) * 1.44269504f);
            const float2 cvv = ((const float2*)cv)[slist[i]];
            s += e;
            q0 = fmaf(e, cvv.x, q0);
            q1 = fmaf(e, cvv.y, q1);
        }
    } else {   // all masked -> uniform softmax
        for (int i = t; i < PP; i += 256) {
            const float2 cvv = ((const float2*)cv)[i];
            s += 1.0f; q0 += cvv.x; q1 += cvv.y;
        }
    }
    #pragma unroll
    for (int off = 32; off; off >>= 1) {
        s  += __shfl_xor(s, off);
        q0 += __shfl_xor(q0, off);
        q1 += __shfl_xor(q1, off);
    }
    __syncthreads();
    if (lane == 0) {
        sred[4 + wid*3 + 0] = s;
        sred[4 + wid*3 + 1] = q0;
        sred[4 + wid*3 + 2] = q1;
    }
    __syncthreads();
    if (t == 0) {
        float S = 0.0f, Q0 = 0.0f, Q1 = 0.0f;
        #pragma unroll
        for (int w = 0; w < 4; ++w) {
            S  += sred[4 + w*3 + 0];
            Q0 += sred[4 + w*3 + 1];
            Q1 += sred[4 + w*3 + 2];
        }
        const float invS = fast_rcp(S);
        coeff_out[n*2+0] = __expf(-Q0 * invS);
        coeff_out[n*2+1] = __expf(-Q1 * invS);
    }
}

// ------- Kernel C: green MLP via MFMA. Block = 4 rows, wave = 1 row (80 slots) -------
__global__ __launch_bounds__(256) void green_kernel(
    const float* __restrict__ pc,  const float* __restrict__ bc,
    const float* __restrict__ skc, const float* __restrict__ sk,
    const float* __restrict__ vw,
    const float* __restrict__ gw1, const float* __restrict__ gb1,
    const float* __restrict__ gw2, const float* __restrict__ gb2,
    const float* __restrict__ gw3, const float* __restrict__ gb3,
    const float* __restrict__ rw,  const float* __restrict__ rb,
    const float* __restrict__ fw,  const float* __restrict__ fb,
    const float* __restrict__ coeff,
    float* __restrict__ out)
{
    __shared__ unsigned short sinA[GR_ROWS*GR_SLOTS*16]; // bf16 [320][16], k<10 used
    __shared__ unsigned short shb[4][16*64];             // per-wave h-tile, swizzled
    __shared__ float swq[GR_SLOTS];
    __shared__ float sg0[4][64];
    __shared__ float squad[4][64];

    const int t = threadIdx.x;
    const int w = t >> 6, lane = t & 63;
    const int c15 = lane & 15, kg = lane >> 4;
    const int n0 = blockIdx.x * GR_ROWS;

    // ---- weight fragments (per lane, loop-invariant) ----
    V4 Bw1[4], Bw2[2][4], Bw3[2][4];
    #pragma unroll
    for (int nt = 0; nt < 4; ++nt) {
        const int col = c15 + nt*16;
        #pragma unroll
        for (int j2 = 0; j2 < 4; ++j2) {
            const int ka = kg*8 + 2*j2, kb = ka + 1;
            const float va = (ka < 10) ? gw1[ka*64 + col] : 0.0f;
            const float vb = (kb < 10) ? gw1[kb*64 + col] : 0.0f;
            Bw1[nt].u[j2] = cvt_pk_bf16(va, vb);
        }
        #pragma unroll
        for (int kt = 0; kt < 2; ++kt) {
            #pragma unroll
            for (int j2 = 0; j2 < 4; ++j2) {
                const int ka = kt*32 + kg*8 + 2*j2, kb = ka + 1;
                Bw2[kt][nt].u[j2] = cvt_pk_bf16(gw2[ka*64 + col], gw2[kb*64 + col]);
                Bw3[kt][nt].u[j2] = cvt_pk_bf16(gw3[ka*64 + col], gw3[kb*64 + col]);
            }
        }
    }
    float b1c[4], b2c[4], b3c[4];
    #pragma unroll
    for (int nt = 0; nt < 4; ++nt) {
        b1c[nt] = gb1[c15 + nt*16];
        b2c[nt] = gb2[c15 + nt*16];
        b3c[nt] = gb3[c15 + nt*16];
    }

    // ---- G1: build bf16 input rows [4 rows x 80 slots][16] ----
    for (int row = t; row < GR_ROWS*GR_SLOTS; row += 256) {
        const int nl = row / GR_SLOTS;
        const int s  = row - nl*GR_SLOTS;
        const int n  = n0 + nl;
        u32x4 lo = {0u,0u,0u,0u}, hi = {0u,0u,0u,0u};
        if (s <= 64) {
            const float X0 = pc[n*4+0], X1 = pc[n*4+1];
            const float V0 = pc[n*4+2], V1 = pc[n*4+3];
            const float XP0 = bc[n*4+0], XP1 = bc[n*4+1];
            float I6, I7;
            if (s == 64) { I6 = bc[n*4+2]; I7 = bc[n*4+3]; }
            else         { I6 = skc[s*2+0]; I7 = skc[s*2+1]; }
            const float C0 = coeff[n*2+0], C1 = coeff[n*2+1];
            lo[0] = cvt_pk_bf16(X0, X1);
            lo[1] = cvt_pk_bf16(V0, V1);
            lo[2] = cvt_pk_bf16(XP0, XP1);
            lo[3] = cvt_pk_bf16(I6, I7);
            hi[0] = cvt_pk_bf16(C0, C1);
        }
        ((u32x4*)sinA)[row*2 + 0] = lo;
        ((u32x4*)sinA)[row*2 + 1] = hi;
    }
    if (t < GR_SLOTS)
        swq[t] = (t < QQ) ? (1.0f - sk[t]) * vw[t] : 0.0f;
    __syncthreads();

    // ---- G2: per wave, 5 M-tiles of its row ----
    unsigned short* hb = &shb[w][0];
    float qacc[4] = {0.f, 0.f, 0.f, 0.f};

    #pragma unroll 1
    for (int T = 0; T < GR_MT; ++T) {
        const int rm = w*GR_SLOTS + T*16 + c15;
        // layer-1 A-frag (K=32, k>=16 zero)
        V4 A1; A1.u = (u32x4){0u,0u,0u,0u};
        if (kg < 2) A1.u = ((u32x4*)sinA)[rm*2 + kg];

        f32x4 acc1[4];
        #pragma unroll
        for (int nt = 0; nt < 4; ++nt) {
            f32x4 a = {b1c[nt], b1c[nt], b1c[nt], b1c[nt]};
            acc1[nt] = __builtin_amdgcn_mfma_f32_16x16x32_bf16(A1.s, Bw1[nt].s, a, 0, 0, 0);
        }
        // tanh + store to wave-private swizzled h-tile
        #pragma unroll
        for (int nt = 0; nt < 4; ++nt) {
            #pragma unroll
            for (int r = 0; r < 4; ++r) {
                const int rl = kg*4 + r;
                hb[rl*64 + ((c15 + nt*16) ^ ((rl&7)<<3))] = bf16_bits(fast_tanh(acc1[nt][r]));
            }
        }
        // layer-2
        V4 A2[2];
        #pragma unroll
        for (int kt = 0; kt < 2; ++kt)
            A2[kt].u = ((u32x4*)hb)[(c15*64 + ((kt*32 + kg*8) ^ ((c15&7)<<3))) >> 3];
        f32x4 acc2[4];
        #pragma unroll
        for (int nt = 0; nt < 4; ++nt) {
            f32x4 a = {b2c[nt], b2c[nt], b2c[nt], b2c[nt]};
            a = __builtin_amdgcn_mfma_f32_16x16x32_bf16(A2[0].s, Bw2[0][nt].s, a, 0, 0, 0);
            acc2[nt] = __builtin_amdgcn_mfma_f32_16x16x32_bf16(A2[1].s, Bw2[1][nt].s, a, 0, 0, 0);
        }
        #pragma unroll
        for (int nt = 0; nt < 4; ++nt) {
            #pragma unroll
            for (int r = 0; r < 4; ++r) {
                const int rl = kg*4 + r;
                hb[rl*64 + ((c15 + nt*16) ^ ((rl&7)<<3))] = bf16_bits(fast_tanh(acc2[nt][r]));
            }
        }
        // layer-3
        V4 A3[2];
        #pragma unroll
        for (int kt = 0; kt < 2; ++kt)
            A3[kt].u = ((u32x4*)hb)[(c15*64 + ((kt*32 + kg*8) ^ ((c15&7)<<3))) >> 3];
        f32x4 acc3[4];
        #pragma unroll
        for (int nt = 0; nt < 4; ++nt) {
            f32x4 a = {b3c[nt], b3c[nt], b3c[nt], b3c[nt]};
            a = __builtin_amdgcn_mfma_f32_16x16x32_bf16(A3[0].s, Bw3[0][nt].s, a, 0, 0, 0);
            acc3[nt] = __builtin_amdgcn_mfma_f32_16x16x32_bf16(A3[1].s, Bw3[1][nt].s, a, 0, 0, 0);
        }
        // g = exp(tanh(.)), quad accumulate + g0 capture
        #pragma unroll
        for (int r = 0; r < 4; ++r) {
            const int s = T*16 + kg*4 + r;
            const float wq = swq[s];
            #pragma unroll
            for (int nt = 0; nt < 4; ++nt) {
                const float g = __expf(fast_tanh(acc3[nt][r]));
                qacc[nt] = fmaf(wq, g, qacc[nt]);
                if (T == GR_MT-1 && kg == 0 && r == 0) sg0[w][c15 + nt*16] = g;
            }
        }
    }

    // reduce quad over kg groups (wave-private)
    #pragma unroll
    for (int nt = 0; nt < 4; ++nt) {
        qacc[nt] += __shfl_xor(qacc[nt], 16);
        qacc[nt] += __shfl_xor(qacc[nt], 32);
    }
    if (kg == 0) {
        #pragma unroll
        for (int nt = 0; nt < 4; ++nt) squad[w][c15 + nt*16] = qacc[nt];
    }

    // ---- G3: res + final (wave-private) ----
    const int k = lane;
    float r0a = rb[k], r1a = 0.f, r2a = 0.f, r3a = 0.f;
    #pragma unroll
    for (int j = 0; j < 64; j += 4) {
        const float4 qd = *(const float4*)&squad[w][j];
        r0a = fmaf(qd.x, rw[(j+0)*64 + k], r0a);
        r1a = fmaf(qd.y, rw[(j+1)*64 + k], r1a);
        r2a = fmaf(qd.z, rw[(j+2)*64 + k], r2a);
        r3a = fmaf(qd.w, rw[(j+3)*64 + k], r3a);
    }
    const float resv = fast_tanh((r0a + r1a) + (r2a + r3a));
    float term = (sg0[w][k] + resv) * fw[k];
    #pragma unroll
    for (int off = 32; off; off >>= 1) term += __shfl_xor(term, off);
    if (lane == 0) out[n0 + w] = term + fb[0];
}

extern "C" void kernel_launch(void* const* d_in, const int* in_sizes, int n_in,
                              void* d_out, int out_size, void* d_ws, size_t ws_size,
                              hipStream_t stream) {
    const float* pc  = (const float*)d_in[0];
    const float* bc  = (const float*)d_in[1];
    const float* cp  = (const float*)d_in[2];
    const float* cv  = (const float*)d_in[3];
    const float* skc = (const float*)d_in[4];
    const float* sk  = (const float*)d_in[5];
    const float* vw  = (const float*)d_in[6];
    const float* aw1 = (const float*)d_in[7];
    const float* ab1 = (const float*)d_in[8];
    const float* aw2 = (const float*)d_in[9];
    const float* ab2 = (const float*)d_in[10];
    const float* aw3 = (const float*)d_in[11];
    const float* ab3 = (const float*)d_in[12];
    const float* gw1 = (const float*)d_in[13];
    const float* gb1 = (const float*)d_in[14];
    const float* gw2 = (const float*)d_in[15];
    const float* gb2 = (const float*)d_in[16];
    const float* gw3 = (const float*)d_in[17];
    const float* gb3 = (const float*)d_in[18];
    const float* rw  = (const float*)d_in[19];
    const float* rb  = (const float*)d_in[20];
    const float* fw  = (const float*)d_in[21];
    const float* fb  = (const float*)d_in[22];

    float* coeff = (float*)d_ws;          // N*2 floats = 16 KB (known-safe)
    float* outp  = (float*)d_out;

    attn_kernel<<<NN, 256, 0, stream>>>(pc, cp, cv, aw1, ab1, aw2, ab2, aw3, ab3, coeff);
    green_kernel<<<NN/GR_ROWS, 256, 0, stream>>>(pc, bc, skc, sk, vw,
                                                 gw1, gb1, gw2, gb2, gw3, gb3,
                                                 rw, rb, fw, fb, coeff, outp);
}